// Round 1
// baseline (2555.802 us; speedup 1.0000x reference)
//
#include <hip/hip_runtime.h>
#include <math.h>

#define NPTS 2048
#define BATCH 4
#define RTOT 8192   // BATCH*NPTS
#define KNN16 16

static __device__ __forceinline__ float lrelu_f(float v) {
  return v >= 0.f ? v : 0.2f * v;
}

// ---------------- KNN top-16 (largest pd = -||xi-xj||^2, stable ties) -------
__global__ __launch_bounds__(256) void knn16_kernel(const float* __restrict__ x,
                                                    int* __restrict__ idxout) {
  __shared__ float4 sp[NPTS];  // 32KB: x,y,z,xx
  const int b = blockIdx.y;
  const int tid = threadIdx.x;
  const float* xb = x + (size_t)b * NPTS * 3;
  for (int i = tid; i < NPTS; i += 256) {
    float a0 = xb[i * 3 + 0], a1 = xb[i * 3 + 1], a2 = xb[i * 3 + 2];
    sp[i] = make_float4(a0, a1, a2, a0 * a0 + a1 * a1 + a2 * a2);
  }
  __syncthreads();
  const int n = blockIdx.x * 256 + tid;
  const float4 p = sp[n];
  float bv[KNN16];
  int bi[KNN16];
#pragma unroll
  for (int k = 0; k < KNN16; k++) { bv[k] = -INFINITY; bi[k] = 0; }
  for (int m = 0; m < NPTS; m++) {
    const float4 q = sp[m];
    const float dot = p.x * q.x + p.y * q.y + p.z * q.z;
    const float inner = -2.0f * dot;
    const float pd = -p.w - inner - q.w;  // matches reference formula
    if (pd > bv[KNN16 - 1]) {             // strict >: equal keeps earlier (lower) index
      bv[KNN16 - 1] = pd; bi[KNN16 - 1] = m;
#pragma unroll
      for (int k = KNN16 - 1; k >= 1; k--) {
        if (bv[k] > bv[k - 1]) {
          float tv = bv[k]; bv[k] = bv[k - 1]; bv[k - 1] = tv;
          int ti = bi[k]; bi[k] = bi[k - 1]; bi[k - 1] = ti;
        }
      }
    }
  }
  int* op = idxout + ((size_t)b * NPTS + n) * KNN16;
#pragma unroll
  for (int k = 0; k < KNN16; k++) op[k] = bi[k];
}

// -------- stack [W_d ; W_c - W_d] : W (O,2C) -> Wout (2O,C) -----------------
__global__ void prep_edge_w(const float* __restrict__ W, float* __restrict__ Wout,
                            int O, int C) {
  int i = blockIdx.x * 256 + threadIdx.x;
  if (i >= 2 * O * C) return;
  int o = i / C, c = i % C;
  Wout[i] = (o < O) ? W[(size_t)o * 2 * C + c]
                    : (W[(size_t)(o - O) * 2 * C + C + c] - W[(size_t)(o - O) * 2 * C + c]);
}

// -------- generic fp32 GEMM: Out(r, o) = sum_k F[r*ldF+k] * W[o*K+k] --------
__global__ __launch_bounds__(256) void gemm_f32(
    const float* __restrict__ F, int ldF,
    const float* __restrict__ W,
    float* __restrict__ Out, int ldOut, int outOff,
    int K, int O) {
  __shared__ __align__(16) float Fs[16][68];
  __shared__ __align__(16) float Ws[16][68];
  const int tid = threadIdx.x;
  const int tx = tid & 15;
  const int ty = tid >> 4;
  const int obase = blockIdx.x * 64;
  const int rbase = blockIdx.y * 64;
  float acc[4][4] = {{0.f}};
  for (int k0 = 0; k0 < K; k0 += 16) {
#pragma unroll
    for (int e = 0; e < 4; e++) {
      int ei = tid * 4 + e;
      int rr = ei >> 4;
      int kk = ei & 15;
      int kg = k0 + kk;
      float fv = 0.f, wv = 0.f;
      if (kg < K) {
        fv = F[(size_t)(rbase + rr) * ldF + kg];
        wv = W[(size_t)(obase + rr) * K + kg];
      }
      Fs[kk][rr] = fv;
      Ws[kk][rr] = wv;
    }
    __syncthreads();
#pragma unroll
    for (int kk = 0; kk < 16; kk++) {
      const float4 a = *(const float4*)&Fs[kk][ty * 4];
      const float4 bb = *(const float4*)&Ws[kk][tx * 4];
      float av[4] = {a.x, a.y, a.z, a.w};
      float bvv[4] = {bb.x, bb.y, bb.z, bb.w};
#pragma unroll
      for (int i = 0; i < 4; i++)
#pragma unroll
        for (int j = 0; j < 4; j++) acc[i][j] = fmaf(av[i], bvv[j], acc[i][j]);
    }
    __syncthreads();
  }
#pragma unroll
  for (int i = 0; i < 4; i++) {
    size_t rowp = (size_t)(rbase + ty * 4 + i) * ldOut + outOff + obase + tx * 4;
    float4 v = make_float4(acc[i][0], acc[i][1], acc[i][2], acc[i][3]);
    *(float4*)&Out[rowp] = v;
  }
}

// -------- edge gather: V = Yc + max_k Yd[nbr]; fp64 BN partial stats --------
__global__ __launch_bounds__(256) void edge_gather(
    const float* __restrict__ Y,       // (RTOT, 2O)
    const int* __restrict__ idx,       // (RTOT, 16)
    float* __restrict__ dst, int dstS, int dstOff,
    double* __restrict__ parts,        // [gridDim.x][O][5]
    int O) {
  const int NCH = 128;
  __shared__ int sidx[NCH * KNN16];       // 8KB
  __shared__ double sred[256 * 5];        // 10KB
  const int tid = threadIdx.x;
  const int row0 = blockIdx.x * NCH;
  const int OC = (O < 128) ? O : 128;
  const int subcnt = 256 / OC;
  const int olane = tid % OC;
  const int sub = tid / OC;
  const int o = blockIdx.y * 128 + olane;
  for (int i = tid; i < NCH * KNN16; i += 256) sidx[i] = idx[(size_t)row0 * KNN16 + i];
  __syncthreads();
  const int twoO = 2 * O;
  double s1 = 0, s2 = 0, scr = 0, sc = 0, sc2 = 0;
  for (int nl = sub; nl < NCH; nl += subcnt) {
    const int r = row0 + nl;
    const int bbase = (r >> 11) << 11;  // batch*2048
    const int* ip = &sidx[nl * KNN16];
    float m = -INFINITY, a1 = 0.f, a2 = 0.f;
#pragma unroll
    for (int k = 0; k < KNN16; k++) {
      const int nb = ip[k];
      const float v = Y[(size_t)(bbase + nb) * twoO + o];
      m = fmaxf(m, v);
      a1 += v;
      a2 = fmaf(v, v, a2);
    }
    const float yc = Y[(size_t)r * twoO + O + o];
    dst[(size_t)r * dstS + dstOff + o] = yc + m;
    s1 += a1; s2 += a2; scr += (double)yc * (double)a1;
    sc += yc; sc2 += (double)yc * (double)yc;
  }
  sred[tid * 5 + 0] = s1; sred[tid * 5 + 1] = s2; sred[tid * 5 + 2] = scr;
  sred[tid * 5 + 3] = sc; sred[tid * 5 + 4] = sc2;
  __syncthreads();
  if (sub == 0) {
    for (int j = 1; j < subcnt; j++) {
      const int t2 = tid + j * OC;
      s1 += sred[t2 * 5 + 0]; s2 += sred[t2 * 5 + 1]; scr += sred[t2 * 5 + 2];
      sc += sred[t2 * 5 + 3]; sc2 += sred[t2 * 5 + 4];
    }
    double* pp = &parts[((size_t)blockIdx.x * O + o) * 5];
    pp[0] = s1; pp[1] = s2; pp[2] = scr; pp[3] = sc; pp[4] = sc2;
  }
}

__global__ void finalize_edge(const double* __restrict__ parts, float* __restrict__ mean,
                              float* __restrict__ invs, int O, int nblk) {
  int o = blockIdx.x * 256 + threadIdx.x;
  if (o >= O) return;
  double s1 = 0, s2 = 0, cr = 0, c = 0, c2 = 0;
  for (int k = 0; k < nblk; k++) {
    const double* p = &parts[((size_t)k * O + o) * 5];
    s1 += p[0]; s2 += p[1]; cr += p[2]; c += p[3]; c2 += p[4];
  }
  const double cnt = (double)RTOT * KNN16;
  double m = (s1 + (double)KNN16 * c) / cnt;
  double ev2 = (s2 + 2.0 * cr + (double)KNN16 * c2) / cnt;
  double var = ev2 - m * m;
  mean[o] = (float)m;
  invs[o] = (float)(1.0 / sqrt(var + 1e-5));
}

// -------- plain per-channel stats over (RTOT, O) ----------------------------
__global__ __launch_bounds__(256) void col_stats(const float* __restrict__ X,
                                                 double* __restrict__ parts, int O) {
  const int NCH = 128;
  __shared__ double sred[256 * 2];
  const int tid = threadIdx.x;
  const int row0 = blockIdx.x * NCH;
  const int OC = (O < 256) ? O : 256;
  const int subcnt = 256 / OC;
  const int olane = tid % OC;
  const int sub = tid / OC;
  const int o = blockIdx.y * 256 + olane;
  double s1 = 0, s2 = 0;
  for (int nl = sub; nl < NCH; nl += subcnt) {
    const float v = X[(size_t)(row0 + nl) * O + o];
    s1 += v; s2 += (double)v * (double)v;
  }
  sred[tid * 2 + 0] = s1; sred[tid * 2 + 1] = s2;
  __syncthreads();
  if (sub == 0) {
    for (int j = 1; j < subcnt; j++) {
      s1 += sred[(tid + j * OC) * 2 + 0];
      s2 += sred[(tid + j * OC) * 2 + 1];
    }
    parts[((size_t)blockIdx.x * O + o) * 2 + 0] = s1;
    parts[((size_t)blockIdx.x * O + o) * 2 + 1] = s2;
  }
}

__global__ void finalize_plain(const double* __restrict__ parts, float* __restrict__ mean,
                               float* __restrict__ invs, int O, int nblk) {
  int o = blockIdx.x * 256 + threadIdx.x;
  if (o >= O) return;
  double s1 = 0, s2 = 0;
  for (int k = 0; k < nblk; k++) {
    s1 += parts[((size_t)k * O + o) * 2 + 0];
    s2 += parts[((size_t)k * O + o) * 2 + 1];
  }
  double m = s1 / (double)RTOT;
  double var = s2 / (double)RTOT - m * m;
  mean[o] = (float)m;
  invs[o] = (float)(1.0 / sqrt(var + 1e-5));
}

// -------- in-place BN + LeakyReLU over (RTOT, O) at stride/colOff -----------
__global__ void bn_apply(float* __restrict__ X, const float* __restrict__ mean,
                         const float* __restrict__ invs, int O, int stride, int colOff) {
  size_t i = (size_t)blockIdx.x * 256 + threadIdx.x;
  if (i >= (size_t)RTOT * O) return;
  int o = (int)(i % O);
  size_t r = i / O;
  float* p = &X[r * stride + colOff + o];
  float v = (*p - mean[o]) * invs[o];
  *p = lrelu_f(v);
}

// -------- g = concat(max_n, mean_n) of H5 (RTOT,1024) -----------------------
__global__ __launch_bounds__(256) void reduce_part(const float* __restrict__ H,
                                                   float* __restrict__ part) {
  const int chunk = blockIdx.x;  // 128 chunks of 64 rows
  const int row0 = chunk * 64;
  const int tid = threadIdx.x;
  float mx[4] = {-INFINITY, -INFINITY, -INFINITY, -INFINITY};
  float sm[4] = {0.f, 0.f, 0.f, 0.f};
  for (int nl = 0; nl < 64; nl++) {
    const float* row = &H[(size_t)(row0 + nl) * 1024];
#pragma unroll
    for (int oi = 0; oi < 4; oi++) {
      float v = row[tid + oi * 256];
      mx[oi] = fmaxf(mx[oi], v);
      sm[oi] += v;
    }
  }
#pragma unroll
  for (int oi = 0; oi < 4; oi++) {
    part[(size_t)chunk * 2048 + tid + oi * 256] = mx[oi];
    part[(size_t)chunk * 2048 + 1024 + tid + oi * 256] = sm[oi];
  }
}

__global__ void reduce_final(const float* __restrict__ part, float* __restrict__ g) {
  int i = blockIdx.x * 256 + threadIdx.x;
  if (i >= 4096) return;
  int b = i >> 10, o = i & 1023;
  float mx = -INFINITY, sm = 0.f;
  for (int c = 0; c < 32; c++) {
    const float* p = &part[(size_t)(b * 32 + c) * 2048];
    mx = fmaxf(mx, p[o]);
    sm += p[1024 + o];
  }
  g[b * 2048 + o] = mx;
  g[b * 2048 + 1024 + o] = sm * (1.0f / 2048.0f);
}

// -------- latent = lrelu(BN_over_batch(g @ W^T)) ----------------------------
__global__ __launch_bounds__(256) void linear1_bn(const float* __restrict__ g,
                                                  const float* __restrict__ W,
                                                  float* __restrict__ latent) {
  __shared__ __align__(16) float sg[4][2048];  // 32KB
  const int tid = threadIdx.x;
  for (int i = tid; i < 4 * 2048; i += 256) sg[i >> 11][i & 2047] = g[i];
  __syncthreads();
  const int wave = tid >> 6, lane = tid & 63;
  const int o = blockIdx.x * 4 + wave;
  const float* wr = &W[(size_t)o * 2048];
  float a0 = 0.f, a1 = 0.f, a2 = 0.f, a3 = 0.f;
  for (int k = lane * 4; k < 2048; k += 256) {
    float4 w4 = *(const float4*)&wr[k];
    float4 x0 = *(const float4*)&sg[0][k];
    float4 x1 = *(const float4*)&sg[1][k];
    float4 x2 = *(const float4*)&sg[2][k];
    float4 x3 = *(const float4*)&sg[3][k];
    a0 += w4.x * x0.x + w4.y * x0.y + w4.z * x0.z + w4.w * x0.w;
    a1 += w4.x * x1.x + w4.y * x1.y + w4.z * x1.z + w4.w * x1.w;
    a2 += w4.x * x2.x + w4.y * x2.y + w4.z * x2.z + w4.w * x2.w;
    a3 += w4.x * x3.x + w4.y * x3.y + w4.z * x3.z + w4.w * x3.w;
  }
  for (int s = 32; s > 0; s >>= 1) {
    a0 += __shfl_down(a0, s); a1 += __shfl_down(a1, s);
    a2 += __shfl_down(a2, s); a3 += __shfl_down(a3, s);
  }
  if (lane == 0) {
    float m = (a0 + a1 + a2 + a3) * 0.25f;
    float d0 = a0 - m, d1 = a1 - m, d2 = a2 - m, d3 = a3 - m;
    float var = (d0 * d0 + d1 * d1 + d2 * d2 + d3 * d3) * 0.25f;
    float inv = 1.0f / sqrtf(var + 1e-5f);
    latent[0 * 2048 + o] = lrelu_f(d0 * inv);
    latent[1 * 2048 + o] = lrelu_f(d1 * inv);
    latent[2 * 2048 + o] = lrelu_f(d2 * inv);
    latent[3 * 2048 + o] = lrelu_f(d3 * inv);
  }
}

// -------- generic fc: out[b][o] = act(dot(X[b], W[o]) + bias[o]) ------------
__global__ __launch_bounds__(256) void fc_wave(const float* __restrict__ X,  // (4,K)
                                               const float* __restrict__ W,
                                               const float* __restrict__ bias,
                                               float* __restrict__ out,
                                               int K, int O, int relu) {
  extern __shared__ float sx[];  // 4*K
  const int tid = threadIdx.x;
  for (int i = tid; i < 4 * K; i += 256) sx[i] = X[i];
  __syncthreads();
  const int wave = tid >> 6, lane = tid & 63;
#pragma unroll
  for (int oi = 0; oi < 4; oi++) {
    const int o = blockIdx.x * 16 + wave * 4 + oi;
    if (o >= O) continue;
    const float* wr = &W[(size_t)o * K];
    float a0 = 0.f, a1 = 0.f, a2 = 0.f, a3 = 0.f;
    for (int k = lane * 4; k < K; k += 256) {
      float4 w4 = *(const float4*)&wr[k];
      float4 x0 = *(const float4*)&sx[0 * K + k];
      float4 x1 = *(const float4*)&sx[1 * K + k];
      float4 x2 = *(const float4*)&sx[2 * K + k];
      float4 x3 = *(const float4*)&sx[3 * K + k];
      a0 += w4.x * x0.x + w4.y * x0.y + w4.z * x0.z + w4.w * x0.w;
      a1 += w4.x * x1.x + w4.y * x1.y + w4.z * x1.z + w4.w * x1.w;
      a2 += w4.x * x2.x + w4.y * x2.y + w4.z * x2.z + w4.w * x2.w;
      a3 += w4.x * x3.x + w4.y * x3.y + w4.z * x3.z + w4.w * x3.w;
    }
    for (int s = 32; s > 0; s >>= 1) {
      a0 += __shfl_down(a0, s); a1 += __shfl_down(a1, s);
      a2 += __shfl_down(a2, s); a3 += __shfl_down(a3, s);
    }
    if (lane == 0) {
      float bb = bias[o];
      float v0 = a0 + bb, v1 = a1 + bb, v2 = a2 + bb, v3 = a3 + bb;
      if (relu) {
        v0 = fmaxf(v0, 0.f); v1 = fmaxf(v1, 0.f);
        v2 = fmaxf(v2, 0.f); v3 = fmaxf(v3, 0.f);
      }
      out[0 * O + o] = v0; out[1 * O + o] = v1;
      out[2 * O + o] = v2; out[3 * O + o] = v3;
    }
  }
}

// -------- small conv1d: out[b][o][j] = act(sum_c W[o][c] X[b][c][j] + b) ----
__global__ void conv1d_small(const float* __restrict__ X, const float* __restrict__ W,
                             const float* __restrict__ bias, float* __restrict__ out,
                             int C, int J, int O2, int relu) {
  int i = blockIdx.x * 256 + threadIdx.x;
  if (i >= 4 * O2 * J) return;
  int j = i % J;
  int o = (i / J) % O2;
  int b = i / (J * O2);
  const float* xb = &X[(size_t)b * C * J + j];
  const float* wr = &W[(size_t)o * C];
  float a = 0.f;
  for (int c = 0; c < C; c++) a = fmaf(wr[c], xb[(size_t)c * J], a);
  a += bias[o];
  if (relu) a = fmaxf(a, 0.f);
  out[i] = a;
}

// -------- mirror expansions + final outputs ---------------------------------
__global__ void finals_kernel(const float* __restrict__ pc1buf,   // (B,3,64)
                              const float* __restrict__ pc2xyz,   // (B,3,128)
                              const float* __restrict__ pc3xyz,   // (B,3,512)
                              float* __restrict__ out) {
  const int b = blockIdx.x;
  __shared__ float p1[3][64];
  __shared__ float p2[3][128];
  const int tid = threadIdx.x;  // 128 threads
  for (int i = tid; i < 192; i += 128) p1[i / 64][i % 64] = pc1buf[b * 192 + i];
  for (int i = tid; i < 384; i += 128) p2[i / 128][i % 128] = pc2xyz[b * 384 + i];
  __syncthreads();
  // pc_low: out[b][pt][c] = p1[c][pt]
  for (int i = tid; i < 192; i += 128) {
    int pt = i / 3, c = i % 3;
    out[b * 192 + i] = p1[c][pt];
  }
  // stage 1: knn(pc1,1) -> exp1 -> pc_middle
  if (tid < 64) {
    const int i = tid;
    float xs0 = p1[0][i], xs1 = p1[1][i], xs2 = p1[2][i];
    float xxi = xs0 * xs0 + xs1 * xs1 + xs2 * xs2;
    float bestv = -INFINITY;
    int besti = 0;
    for (int m = 0; m < 64; m++) {
      float q0 = p1[0][m], q1 = p1[1][m], q2 = p1[2][m];
      float dot = xs0 * q0 + xs1 * q1 + xs2 * q2;
      float inner = -2.0f * dot;
      float pd = -xxi - inner - (q0 * q0 + q1 * q1 + q2 * q2);
      if (pd > bestv) { bestv = pd; besti = m; }
    }
#pragma unroll
    for (int c = 0; c < 3; c++) {
      float ctr = p1[c][i];
      float nb = p1[c][besti];
      float e0 = 2.0f * ctr - nb;
      float e1 = ctr;
      out[768 + b * 384 + (2 * i) * 3 + c] = e0 + p2[c][2 * i];
      out[768 + b * 384 + (2 * i + 1) * 3 + c] = e1 + p2[c][2 * i + 1];
    }
  }
  // stage 2: knn(pc2,3) -> exp2 -> pc_high
  {
    const int j = tid;  // 128 threads
    float xs0 = p2[0][j], xs1 = p2[1][j], xs2 = p2[2][j];
    float xxj = xs0 * xs0 + xs1 * xs1 + xs2 * xs2;
    float bv0 = -INFINITY, bv1 = -INFINITY, bv2 = -INFINITY;
    int bi0 = 0, bi1 = 0, bi2 = 0;
    for (int m = 0; m < 128; m++) {
      float q0 = p2[0][m], q1 = p2[1][m], q2 = p2[2][m];
      float dot = xs0 * q0 + xs1 * q1 + xs2 * q2;
      float inner = -2.0f * dot;
      float pd = -xxj - inner - (q0 * q0 + q1 * q1 + q2 * q2);
      if (pd > bv2) {
        bv2 = pd; bi2 = m;
        if (bv2 > bv1) { float t = bv2; bv2 = bv1; bv1 = t; int ti = bi2; bi2 = bi1; bi1 = ti; }
        if (bv1 > bv0) { float t = bv1; bv1 = bv0; bv0 = t; int ti = bi1; bi1 = bi0; bi0 = ti; }
      }
    }
#pragma unroll
    for (int c = 0; c < 3; c++) {
      float ctr = p2[c][j];
      float e0 = 2.0f * ctr - p2[c][bi0];
      float e1 = 2.0f * ctr - p2[c][bi1];
      float e2 = 2.0f * ctr - p2[c][bi2];
      float e3 = ctr;
      const float* p3 = &pc3xyz[b * 1536 + c * 512];
      out[2304 + b * 1536 + (4 * j + 0) * 3 + c] = e0 + p3[4 * j + 0];
      out[2304 + b * 1536 + (4 * j + 1) * 3 + c] = e1 + p3[4 * j + 1];
      out[2304 + b * 1536 + (4 * j + 2) * 3 + c] = e2 + p3[4 * j + 2];
      out[2304 + b * 1536 + (4 * j + 3) * 3 + c] = e3 + p3[4 * j + 3];
    }
  }
}

extern "C" void kernel_launch(void* const* d_in, const int* in_sizes, int n_in,
                              void* d_out, int out_size, void* d_ws, size_t ws_size,
                              hipStream_t stream) {
  (void)in_sizes; (void)n_in; (void)out_size; (void)ws_size;
  const float* x          = (const float*)d_in[0];
  const float* conv1_w    = (const float*)d_in[1];
  const float* conv2_w    = (const float*)d_in[2];
  const float* conv2_1_w  = (const float*)d_in[3];
  const float* conv3_w    = (const float*)d_in[4];
  const float* conv3_1_w  = (const float*)d_in[5];
  const float* conv4_w    = (const float*)d_in[6];
  const float* conv5_w    = (const float*)d_in[7];
  const float* linear1_w  = (const float*)d_in[8];
  const float* fc1_w      = (const float*)d_in[9];
  const float* fc1_b      = (const float*)d_in[10];
  const float* fc2_w      = (const float*)d_in[11];
  const float* fc2_b      = (const float*)d_in[12];
  const float* fc3_w      = (const float*)d_in[13];
  const float* fc3_b      = (const float*)d_in[14];
  const float* fc1_1_w    = (const float*)d_in[15];
  const float* fc1_1_b    = (const float*)d_in[16];
  const float* fc2_1_w    = (const float*)d_in[17];
  const float* fc2_1_b    = (const float*)d_in[18];
  const float* fc3_1_w    = (const float*)d_in[19];
  const float* fc3_1_b    = (const float*)d_in[20];
  const float* g_conv1_1_w = (const float*)d_in[21];
  const float* g_conv1_1_b = (const float*)d_in[22];
  const float* g_conv1_2_w = (const float*)d_in[23];
  const float* g_conv1_2_b = (const float*)d_in[24];
  const float* g_conv2_1_w = (const float*)d_in[25];
  const float* g_conv2_1_b = (const float*)d_in[26];

  char* ws = (char*)d_ws;
  size_t off = 0;
  auto alloc = [&](size_t bytes) -> void* {
    off = (off + 511) & ~((size_t)511);
    void* p = ws + off;
    off += bytes;
    return p;
  };

  int*    idx0   = (int*)alloc((size_t)RTOT * 16 * 4);
  float*  ws1    = (float*)alloc((size_t)2 * 64 * 3 * 4);
  float*  ws2    = (float*)alloc((size_t)2 * 64 * 64 * 4);
  float*  ws3    = (float*)alloc((size_t)2 * 128 * 128 * 4);
  float*  ws4    = (float*)alloc((size_t)2 * 512 * 256 * 4);
  float*  ydyc   = (float*)alloc((size_t)RTOT * 1024 * 4);
  float*  xcat   = (float*)alloc((size_t)RTOT * 768 * 4);
  float*  h1     = (float*)alloc((size_t)RTOT * 128 * 4);
  float*  h2     = (float*)alloc((size_t)RTOT * 256 * 4);
  float*  h5     = (float*)alloc((size_t)RTOT * 1024 * 4);
  double* parts  = (double*)alloc((size_t)64 * 1024 * 5 * 8);
  float*  meanb  = (float*)alloc(1024 * 4);
  float*  invb   = (float*)alloc(1024 * 4);
  float*  gpart  = (float*)alloc((size_t)128 * 2048 * 4);
  float*  gvec   = (float*)alloc((size_t)4 * 2048 * 4);
  float*  latent = (float*)alloc((size_t)4 * 2048 * 4);
  float*  x1v    = (float*)alloc((size_t)4 * 1024 * 4);
  float*  x2v    = (float*)alloc((size_t)4 * 512 * 4);
  float*  x3v    = (float*)alloc((size_t)4 * 256 * 4);
  float*  pc1    = (float*)alloc((size_t)4 * 192 * 4);
  float*  pc2f   = (float*)alloc((size_t)4 * 8192 * 4);
  float*  pc2xyz = (float*)alloc((size_t)4 * 384 * 4);
  float*  pc3f   = (float*)alloc((size_t)4 * 65536 * 4);
  float*  pc3f2  = (float*)alloc((size_t)4 * 64 * 512 * 4);
  float*  pc3xyz = (float*)alloc((size_t)4 * 1536 * 4);

  // ---- KNN graph (shared by all edge layers)
  knn16_kernel<<<dim3(8, 4), 256, 0, stream>>>(x, idx0);

  // ---- conv1 (edge, C=3, O=64) -> xcat cols [0,64)
  prep_edge_w<<<(2 * 64 * 3 + 255) / 256, 256, 0, stream>>>(conv1_w, ws1, 64, 3);
  gemm_f32<<<dim3(2, RTOT / 64), 256, 0, stream>>>(x, 3, ws1, ydyc, 128, 0, 3, 128);
  edge_gather<<<dim3(64, 1), 256, 0, stream>>>(ydyc, idx0, xcat, 768, 0, parts, 64);
  finalize_edge<<<1, 256, 0, stream>>>(parts, meanb, invb, 64, 64);
  bn_apply<<<(RTOT * 64) / 256, 256, 0, stream>>>(xcat, meanb, invb, 64, 768, 0);

  // ---- conv2 (edge, C=64, O=64) -> xcat cols [64,128)
  prep_edge_w<<<(2 * 64 * 64 + 255) / 256, 256, 0, stream>>>(conv2_w, ws2, 64, 64);
  gemm_f32<<<dim3(2, RTOT / 64), 256, 0, stream>>>(xcat, 768, ws2, ydyc, 128, 0, 64, 128);
  edge_gather<<<dim3(64, 1), 256, 0, stream>>>(ydyc, idx0, xcat, 768, 64, parts, 64);
  finalize_edge<<<1, 256, 0, stream>>>(parts, meanb, invb, 64, 64);
  bn_apply<<<(RTOT * 64) / 256, 256, 0, stream>>>(xcat, meanb, invb, 64, 768, 64);

  // ---- conv2_1 (plain, K=128, O=128) -> h1
  gemm_f32<<<dim3(2, RTOT / 64), 256, 0, stream>>>(xcat, 768, conv2_1_w, h1, 128, 0, 128, 128);
  col_stats<<<dim3(64, 1), 256, 0, stream>>>(h1, parts, 128);
  finalize_plain<<<1, 256, 0, stream>>>(parts, meanb, invb, 128, 64);
  bn_apply<<<(RTOT * 128) / 256, 256, 0, stream>>>(h1, meanb, invb, 128, 128, 0);

  // ---- conv3 (edge, C=128, O=128) -> xcat cols [128,256)
  prep_edge_w<<<(2 * 128 * 128 + 255) / 256, 256, 0, stream>>>(conv3_w, ws3, 128, 128);
  gemm_f32<<<dim3(4, RTOT / 64), 256, 0, stream>>>(h1, 128, ws3, ydyc, 256, 0, 128, 256);
  edge_gather<<<dim3(64, 1), 256, 0, stream>>>(ydyc, idx0, xcat, 768, 128, parts, 128);
  finalize_edge<<<1, 256, 0, stream>>>(parts, meanb, invb, 128, 64);
  bn_apply<<<(RTOT * 128) / 256, 256, 0, stream>>>(xcat, meanb, invb, 128, 768, 128);

  // ---- conv3_1 (plain, K=256, O=256) -> h2
  gemm_f32<<<dim3(4, RTOT / 64), 256, 0, stream>>>(xcat, 768, conv3_1_w, h2, 256, 0, 256, 256);
  col_stats<<<dim3(64, 1), 256, 0, stream>>>(h2, parts, 256);
  finalize_plain<<<1, 256, 0, stream>>>(parts, meanb, invb, 256, 64);
  bn_apply<<<(RTOT * 256) / 256, 256, 0, stream>>>(h2, meanb, invb, 256, 256, 0);

  // ---- conv4 (edge, C=256, O=512) -> xcat cols [256,768)
  prep_edge_w<<<(2 * 512 * 256 + 255) / 256, 256, 0, stream>>>(conv4_w, ws4, 512, 256);
  gemm_f32<<<dim3(16, RTOT / 64), 256, 0, stream>>>(h2, 256, ws4, ydyc, 1024, 0, 256, 1024);
  edge_gather<<<dim3(64, 4), 256, 0, stream>>>(ydyc, idx0, xcat, 768, 256, parts, 512);
  finalize_edge<<<2, 256, 0, stream>>>(parts, meanb, invb, 512, 64);
  bn_apply<<<(RTOT * 512) / 256, 256, 0, stream>>>(xcat, meanb, invb, 512, 768, 256);

  // ---- conv5 (plain, K=768, O=1024) -> h5
  gemm_f32<<<dim3(16, RTOT / 64), 256, 0, stream>>>(xcat, 768, conv5_w, h5, 1024, 0, 768, 1024);
  col_stats<<<dim3(64, 4), 256, 0, stream>>>(h5, parts, 1024);
  finalize_plain<<<4, 256, 0, stream>>>(parts, meanb, invb, 1024, 64);
  bn_apply<<<(RTOT * 1024) / 256, 256, 0, stream>>>(h5, meanb, invb, 1024, 1024, 0);

  // ---- g = concat(max, mean)
  reduce_part<<<128, 256, 0, stream>>>(h5, gpart);
  reduce_final<<<16, 256, 0, stream>>>(gpart, gvec);

  // ---- latent
  linear1_bn<<<512, 256, 0, stream>>>(gvec, linear1_w, latent);

  // ---- fc chain
  fc_wave<<<1024 / 16, 256, 4 * 2048 * 4, stream>>>(latent, fc1_w, fc1_b, x1v, 2048, 1024, 1);
  fc_wave<<<512 / 16, 256, 4 * 1024 * 4, stream>>>(x1v, fc2_w, fc2_b, x2v, 1024, 512, 1);
  fc_wave<<<256 / 16, 256, 4 * 512 * 4, stream>>>(x2v, fc3_w, fc3_b, x3v, 512, 256, 1);
  fc_wave<<<192 / 16, 256, 4 * 256 * 4, stream>>>(x3v, fc3_1_w, fc3_1_b, pc1, 256, 192, 0);
  fc_wave<<<8192 / 16, 256, 4 * 512 * 4, stream>>>(x2v, fc2_1_w, fc2_1_b, pc2f, 512, 8192, 1);
  fc_wave<<<65536 / 16, 256, 4 * 1024 * 4, stream>>>(x1v, fc1_1_w, fc1_1_b, pc3f, 1024, 65536, 1);

  // ---- decoder convs
  conv1d_small<<<(4 * 3 * 128 + 255) / 256, 256, 0, stream>>>(pc2f, g_conv2_1_w, g_conv2_1_b,
                                                              pc2xyz, 64, 128, 3, 0);
  conv1d_small<<<(4 * 64 * 512 + 255) / 256, 256, 0, stream>>>(pc3f, g_conv1_1_w, g_conv1_1_b,
                                                               pc3f2, 128, 512, 64, 1);
  conv1d_small<<<(4 * 3 * 512 + 255) / 256, 256, 0, stream>>>(pc3f2, g_conv1_2_w, g_conv1_2_b,
                                                              pc3xyz, 64, 512, 3, 0);

  // ---- mirror expansions + outputs
  finals_kernel<<<4, 128, 0, stream>>>(pc1, pc2xyz, pc3xyz, (float*)d_out);
}

// Round 2
// 1708.746 us; speedup vs baseline: 1.4957x; 1.4957x over previous
//
#include <hip/hip_runtime.h>
#include <math.h>

#define NPTS 2048
#define BATCH 4
#define RTOT 8192   // BATCH*NPTS
#define KNN16 16

typedef unsigned long long u64;

static __device__ __forceinline__ float lrelu_f(float v) {
  return v >= 0.f ? v : 0.2f * v;
}

// ====================== KNN top-16, two-pass, register CE chain =============
// key = (sortable_fp32(pd) << 32) | (2047 - m)  -> u64 max-order == (pd desc, m asc)
#define REP16(X) X(0) X(1) X(2) X(3) X(4) X(5) X(6) X(7) X(8) X(9) X(10) X(11) X(12) X(13) X(14) X(15)

__global__ __launch_bounds__(256) void knn16_part(const float* __restrict__ x,
                                                  u64* __restrict__ pkeys) {
  __shared__ float4 cand[256];
  const int tid = threadIdx.x;
  const int qchunk = blockIdx.x, slice = blockIdx.y, b = blockIdx.z;
  const float* xb = x + (size_t)b * NPTS * 3;
  {
    const int c = slice * 256 + tid;
    float a0 = xb[c * 3 + 0], a1 = xb[c * 3 + 1], a2 = xb[c * 3 + 2];
    cand[tid] = make_float4(a0, a1, a2, a0 * a0 + a1 * a1 + a2 * a2);
  }
  const int n = qchunk * 256 + tid;
  const float p0 = xb[n * 3 + 0], p1 = xb[n * 3 + 1], p2 = xb[n * 3 + 2];
  const float pw = p0 * p0 + p1 * p1 + p2 * p2;
  __syncthreads();

#define DECLK(k) u64 key##k = 0ull;
  REP16(DECLK)
#undef DECLK
  const int mbase = slice * 256;
  for (int m2 = 0; m2 < 256; m2++) {
    const float4 qd = cand[m2];
    const float dot = p0 * qd.x + p1 * qd.y + p2 * qd.z;
    const float inner = -2.0f * dot;
    const float pd = -pw - inner - qd.w;  // matches reference formula
    unsigned int s = __float_as_uint(pd);
    s = (s & 0x80000000u) ? ~s : (s | 0x80000000u);
    u64 ck = ((u64)s << 32) | (unsigned int)(2047 - (mbase + m2));
#define CE(k) { const bool sw = ck > key##k; const u64 mx = sw ? ck : key##k; \
                const u64 mn = sw ? key##k : ck; key##k = mx; ck = mn; }
    REP16(CE)
#undef CE
  }
  const size_t q = (size_t)b * NPTS + n;
#define STOREK(k) pkeys[(size_t)(slice * 16 + k) * RTOT + q] = key##k;
  REP16(STOREK)
#undef STOREK
}

__global__ __launch_bounds__(256) void knn16_merge(const u64* __restrict__ pkeys,
                                                   int* __restrict__ idxout) {
  const int q = blockIdx.x * 256 + threadIdx.x;
#define DECLK(k) u64 key##k = 0ull;
  REP16(DECLK)
#undef DECLK
  for (int j = 0; j < 128; j++) {
    u64 ck = pkeys[(size_t)j * RTOT + q];
#define CE(k) { const bool sw = ck > key##k; const u64 mx = sw ? ck : key##k; \
                const u64 mn = sw ? key##k : ck; key##k = mx; ck = mn; }
    REP16(CE)
#undef CE
  }
  int* op = idxout + (size_t)q * KNN16;
#define STOREI(k) op[k] = 2047 - (int)(key##k & 0xFFFFFFFFu);
  REP16(STOREI)
#undef STOREI
}

// -------- stack [W_d ; W_c - W_d] : W (O,2C) -> Wout (2O,C) -----------------
__global__ void prep_edge_w(const float* __restrict__ W, float* __restrict__ Wout,
                            int O, int C) {
  int i = blockIdx.x * 256 + threadIdx.x;
  if (i >= 2 * O * C) return;
  int o = i / C, c = i % C;
  Wout[i] = (o < O) ? W[(size_t)o * 2 * C + c]
                    : (W[(size_t)(o - O) * 2 * C + C + c] - W[(size_t)(o - O) * 2 * C + c]);
}

// -------- generic fp32 GEMM: Out(r, o) = sum_k F[r*ldF+k] * W[o*K+k] --------
__global__ __launch_bounds__(256) void gemm_f32(
    const float* __restrict__ F, int ldF,
    const float* __restrict__ W,
    float* __restrict__ Out, int ldOut, int outOff,
    int K, int O) {
  __shared__ __align__(16) float Fs[16][68];
  __shared__ __align__(16) float Ws[16][68];
  const int tid = threadIdx.x;
  const int tx = tid & 15;
  const int ty = tid >> 4;
  const int obase = blockIdx.x * 64;
  const int rbase = blockIdx.y * 64;
  float acc[4][4] = {{0.f}};
  for (int k0 = 0; k0 < K; k0 += 16) {
#pragma unroll
    for (int e = 0; e < 4; e++) {
      int ei = tid * 4 + e;
      int rr = ei >> 4;
      int kk = ei & 15;
      int kg = k0 + kk;
      float fv = 0.f, wv = 0.f;
      if (kg < K) {
        fv = F[(size_t)(rbase + rr) * ldF + kg];
        wv = W[(size_t)(obase + rr) * K + kg];
      }
      Fs[kk][rr] = fv;
      Ws[kk][rr] = wv;
    }
    __syncthreads();
#pragma unroll
    for (int kk = 0; kk < 16; kk++) {
      const float4 a = *(const float4*)&Fs[kk][ty * 4];
      const float4 bb = *(const float4*)&Ws[kk][tx * 4];
      float av[4] = {a.x, a.y, a.z, a.w};
      float bvv[4] = {bb.x, bb.y, bb.z, bb.w};
#pragma unroll
      for (int i = 0; i < 4; i++)
#pragma unroll
        for (int j = 0; j < 4; j++) acc[i][j] = fmaf(av[i], bvv[j], acc[i][j]);
    }
    __syncthreads();
  }
#pragma unroll
  for (int i = 0; i < 4; i++) {
    size_t rowp = (size_t)(rbase + ty * 4 + i) * ldOut + outOff + obase + tx * 4;
    float4 v = make_float4(acc[i][0], acc[i][1], acc[i][2], acc[i][3]);
    *(float4*)&Out[rowp] = v;
  }
}

// -------- edge gather: V = Yc + max_k Yd[nbr]; fp64 BN partial stats --------
__global__ __launch_bounds__(256) void edge_gather(
    const float* __restrict__ Y,       // (RTOT, 2O)
    const int* __restrict__ idx,       // (RTOT, 16)
    float* __restrict__ dst, int dstS, int dstOff,
    double* __restrict__ parts,        // [gridDim.x][O][5]
    int O) {
  const int NCH = 128;
  __shared__ int sidx[NCH * KNN16];       // 8KB
  __shared__ double sred[256 * 5];        // 10KB
  const int tid = threadIdx.x;
  const int row0 = blockIdx.x * NCH;
  const int OC = (O < 128) ? O : 128;
  const int subcnt = 256 / OC;
  const int olane = tid % OC;
  const int sub = tid / OC;
  const int o = blockIdx.y * 128 + olane;
  for (int i = tid; i < NCH * KNN16; i += 256) sidx[i] = idx[(size_t)row0 * KNN16 + i];
  __syncthreads();
  const int twoO = 2 * O;
  double s1 = 0, s2 = 0, scr = 0, sc = 0, sc2 = 0;
  for (int nl = sub; nl < NCH; nl += subcnt) {
    const int r = row0 + nl;
    const int bbase = (r >> 11) << 11;  // batch*2048
    const int* ip = &sidx[nl * KNN16];
    float m = -INFINITY, a1 = 0.f, a2 = 0.f;
#pragma unroll
    for (int k = 0; k < KNN16; k++) {
      const int nb = ip[k];
      const float v = Y[(size_t)(bbase + nb) * twoO + o];
      m = fmaxf(m, v);
      a1 += v;
      a2 = fmaf(v, v, a2);
    }
    const float yc = Y[(size_t)r * twoO + O + o];
    dst[(size_t)r * dstS + dstOff + o] = yc + m;
    s1 += a1; s2 += a2; scr += (double)yc * (double)a1;
    sc += yc; sc2 += (double)yc * (double)yc;
  }
  sred[tid * 5 + 0] = s1; sred[tid * 5 + 1] = s2; sred[tid * 5 + 2] = scr;
  sred[tid * 5 + 3] = sc; sred[tid * 5 + 4] = sc2;
  __syncthreads();
  if (sub == 0) {
    for (int j = 1; j < subcnt; j++) {
      const int t2 = tid + j * OC;
      s1 += sred[t2 * 5 + 0]; s2 += sred[t2 * 5 + 1]; scr += sred[t2 * 5 + 2];
      sc += sred[t2 * 5 + 3]; sc2 += sred[t2 * 5 + 4];
    }
    double* pp = &parts[((size_t)blockIdx.x * O + o) * 5];
    pp[0] = s1; pp[1] = s2; pp[2] = scr; pp[3] = sc; pp[4] = sc2;
  }
}

__global__ void finalize_edge(const double* __restrict__ parts, float* __restrict__ mean,
                              float* __restrict__ invs, int O, int nblk) {
  int o = blockIdx.x * 256 + threadIdx.x;
  if (o >= O) return;
  double s1 = 0, s2 = 0, cr = 0, c = 0, c2 = 0;
  for (int k = 0; k < nblk; k++) {
    const double* p = &parts[((size_t)k * O + o) * 5];
    s1 += p[0]; s2 += p[1]; cr += p[2]; c += p[3]; c2 += p[4];
  }
  const double cnt = (double)RTOT * KNN16;
  double m = (s1 + (double)KNN16 * c) / cnt;
  double ev2 = (s2 + 2.0 * cr + (double)KNN16 * c2) / cnt;
  double var = ev2 - m * m;
  mean[o] = (float)m;
  invs[o] = (float)(1.0 / sqrt(var + 1e-5));
}

// -------- plain per-channel stats over (RTOT, O) ----------------------------
__global__ __launch_bounds__(256) void col_stats(const float* __restrict__ X,
                                                 double* __restrict__ parts, int O) {
  const int NCH = 128;
  __shared__ double sred[256 * 2];
  const int tid = threadIdx.x;
  const int row0 = blockIdx.x * NCH;
  const int OC = (O < 256) ? O : 256;
  const int subcnt = 256 / OC;
  const int olane = tid % OC;
  const int sub = tid / OC;
  const int o = blockIdx.y * 256 + olane;
  double s1 = 0, s2 = 0;
  for (int nl = sub; nl < NCH; nl += subcnt) {
    const float v = X[(size_t)(row0 + nl) * O + o];
    s1 += v; s2 += (double)v * (double)v;
  }
  sred[tid * 2 + 0] = s1; sred[tid * 2 + 1] = s2;
  __syncthreads();
  if (sub == 0) {
    for (int j = 1; j < subcnt; j++) {
      s1 += sred[(tid + j * OC) * 2 + 0];
      s2 += sred[(tid + j * OC) * 2 + 1];
    }
    parts[((size_t)blockIdx.x * O + o) * 2 + 0] = s1;
    parts[((size_t)blockIdx.x * O + o) * 2 + 1] = s2;
  }
}

__global__ void finalize_plain(const double* __restrict__ parts, float* __restrict__ mean,
                               float* __restrict__ invs, int O, int nblk) {
  int o = blockIdx.x * 256 + threadIdx.x;
  if (o >= O) return;
  double s1 = 0, s2 = 0;
  for (int k = 0; k < nblk; k++) {
    s1 += parts[((size_t)k * O + o) * 2 + 0];
    s2 += parts[((size_t)k * O + o) * 2 + 1];
  }
  double m = s1 / (double)RTOT;
  double var = s2 / (double)RTOT - m * m;
  mean[o] = (float)m;
  invs[o] = (float)(1.0 / sqrt(var + 1e-5));
}

// -------- in-place BN + LeakyReLU over (RTOT, O) at stride/colOff -----------
__global__ void bn_apply(float* __restrict__ X, const float* __restrict__ mean,
                         const float* __restrict__ invs, int O, int stride, int colOff) {
  size_t i = (size_t)blockIdx.x * 256 + threadIdx.x;
  if (i >= (size_t)RTOT * O) return;
  int o = (int)(i % O);
  size_t r = i / O;
  float* p = &X[r * stride + colOff + o];
  float v = (*p - mean[o]) * invs[o];
  *p = lrelu_f(v);
}

// -------- g = concat(max_n, mean_n) of H5 (RTOT,1024) -----------------------
__global__ __launch_bounds__(256) void reduce_part(const float* __restrict__ H,
                                                   float* __restrict__ part) {
  const int chunk = blockIdx.x;  // 128 chunks of 64 rows
  const int row0 = chunk * 64;
  const int tid = threadIdx.x;
  float mx[4] = {-INFINITY, -INFINITY, -INFINITY, -INFINITY};
  float sm[4] = {0.f, 0.f, 0.f, 0.f};
  for (int nl = 0; nl < 64; nl++) {
    const float* row = &H[(size_t)(row0 + nl) * 1024];
#pragma unroll
    for (int oi = 0; oi < 4; oi++) {
      float v = row[tid + oi * 256];
      mx[oi] = fmaxf(mx[oi], v);
      sm[oi] += v;
    }
  }
#pragma unroll
  for (int oi = 0; oi < 4; oi++) {
    part[(size_t)chunk * 2048 + tid + oi * 256] = mx[oi];
    part[(size_t)chunk * 2048 + 1024 + tid + oi * 256] = sm[oi];
  }
}

__global__ void reduce_final(const float* __restrict__ part, float* __restrict__ g) {
  int i = blockIdx.x * 256 + threadIdx.x;
  if (i >= 4096) return;
  int b = i >> 10, o = i & 1023;
  float mx = -INFINITY, sm = 0.f;
  for (int c = 0; c < 32; c++) {
    const float* p = &part[(size_t)(b * 32 + c) * 2048];
    mx = fmaxf(mx, p[o]);
    sm += p[1024 + o];
  }
  g[b * 2048 + o] = mx;
  g[b * 2048 + 1024 + o] = sm * (1.0f / 2048.0f);
}

// -------- latent = lrelu(BN_over_batch(g @ W^T)) ----------------------------
__global__ __launch_bounds__(256) void linear1_bn(const float* __restrict__ g,
                                                  const float* __restrict__ W,
                                                  float* __restrict__ latent) {
  __shared__ __align__(16) float sg[4][2048];  // 32KB
  const int tid = threadIdx.x;
  for (int i = tid; i < 4 * 2048; i += 256) sg[i >> 11][i & 2047] = g[i];
  __syncthreads();
  const int wave = tid >> 6, lane = tid & 63;
  const int o = blockIdx.x * 4 + wave;
  const float* wr = &W[(size_t)o * 2048];
  float a0 = 0.f, a1 = 0.f, a2 = 0.f, a3 = 0.f;
  for (int k = lane * 4; k < 2048; k += 256) {
    float4 w4 = *(const float4*)&wr[k];
    float4 x0 = *(const float4*)&sg[0][k];
    float4 x1 = *(const float4*)&sg[1][k];
    float4 x2 = *(const float4*)&sg[2][k];
    float4 x3 = *(const float4*)&sg[3][k];
    a0 += w4.x * x0.x + w4.y * x0.y + w4.z * x0.z + w4.w * x0.w;
    a1 += w4.x * x1.x + w4.y * x1.y + w4.z * x1.z + w4.w * x1.w;
    a2 += w4.x * x2.x + w4.y * x2.y + w4.z * x2.z + w4.w * x2.w;
    a3 += w4.x * x3.x + w4.y * x3.y + w4.z * x3.z + w4.w * x3.w;
  }
  for (int s = 32; s > 0; s >>= 1) {
    a0 += __shfl_down(a0, s); a1 += __shfl_down(a1, s);
    a2 += __shfl_down(a2, s); a3 += __shfl_down(a3, s);
  }
  if (lane == 0) {
    float m = (a0 + a1 + a2 + a3) * 0.25f;
    float d0 = a0 - m, d1 = a1 - m, d2 = a2 - m, d3 = a3 - m;
    float var = (d0 * d0 + d1 * d1 + d2 * d2 + d3 * d3) * 0.25f;
    float inv = 1.0f / sqrtf(var + 1e-5f);
    latent[0 * 2048 + o] = lrelu_f(d0 * inv);
    latent[1 * 2048 + o] = lrelu_f(d1 * inv);
    latent[2 * 2048 + o] = lrelu_f(d2 * inv);
    latent[3 * 2048 + o] = lrelu_f(d3 * inv);
  }
}

// -------- generic fc: out[b][o] = act(dot(X[b], W[o]) + bias[o]) ------------
__global__ __launch_bounds__(256) void fc_wave(const float* __restrict__ X,  // (4,K)
                                               const float* __restrict__ W,
                                               const float* __restrict__ bias,
                                               float* __restrict__ out,
                                               int K, int O, int relu) {
  extern __shared__ float sx[];  // 4*K
  const int tid = threadIdx.x;
  for (int i = tid; i < 4 * K; i += 256) sx[i] = X[i];
  __syncthreads();
  const int wave = tid >> 6, lane = tid & 63;
#pragma unroll
  for (int oi = 0; oi < 4; oi++) {
    const int o = blockIdx.x * 16 + wave * 4 + oi;
    if (o >= O) continue;
    const float* wr = &W[(size_t)o * K];
    float a0 = 0.f, a1 = 0.f, a2 = 0.f, a3 = 0.f;
    for (int k = lane * 4; k < K; k += 256) {
      float4 w4 = *(const float4*)&wr[k];
      float4 x0 = *(const float4*)&sx[0 * K + k];
      float4 x1 = *(const float4*)&sx[1 * K + k];
      float4 x2 = *(const float4*)&sx[2 * K + k];
      float4 x3 = *(const float4*)&sx[3 * K + k];
      a0 += w4.x * x0.x + w4.y * x0.y + w4.z * x0.z + w4.w * x0.w;
      a1 += w4.x * x1.x + w4.y * x1.y + w4.z * x1.z + w4.w * x1.w;
      a2 += w4.x * x2.x + w4.y * x2.y + w4.z * x2.z + w4.w * x2.w;
      a3 += w4.x * x3.x + w4.y * x3.y + w4.z * x3.z + w4.w * x3.w;
    }
    for (int s = 32; s > 0; s >>= 1) {
      a0 += __shfl_down(a0, s); a1 += __shfl_down(a1, s);
      a2 += __shfl_down(a2, s); a3 += __shfl_down(a3, s);
    }
    if (lane == 0) {
      float bb = bias[o];
      float v0 = a0 + bb, v1 = a1 + bb, v2 = a2 + bb, v3 = a3 + bb;
      if (relu) {
        v0 = fmaxf(v0, 0.f); v1 = fmaxf(v1, 0.f);
        v2 = fmaxf(v2, 0.f); v3 = fmaxf(v3, 0.f);
      }
      out[0 * O + o] = v0; out[1 * O + o] = v1;
      out[2 * O + o] = v2; out[3 * O + o] = v3;
    }
  }
}

// -------- small conv1d: out[b][o][j] = act(sum_c W[o][c] X[b][c][j] + b) ----
__global__ void conv1d_small(const float* __restrict__ X, const float* __restrict__ W,
                             const float* __restrict__ bias, float* __restrict__ out,
                             int C, int J, int O2, int relu) {
  int i = blockIdx.x * 256 + threadIdx.x;
  if (i >= 4 * O2 * J) return;
  int j = i % J;
  int o = (i / J) % O2;
  int b = i / (J * O2);
  const float* xb = &X[(size_t)b * C * J + j];
  const float* wr = &W[(size_t)o * C];
  float a = 0.f;
  for (int c = 0; c < C; c++) a = fmaf(wr[c], xb[(size_t)c * J], a);
  a += bias[o];
  if (relu) a = fmaxf(a, 0.f);
  out[i] = a;
}

// -------- mirror expansions + final outputs ---------------------------------
__global__ void finals_kernel(const float* __restrict__ pc1buf,   // (B,3,64)
                              const float* __restrict__ pc2xyz,   // (B,3,128)
                              const float* __restrict__ pc3xyz,   // (B,3,512)
                              float* __restrict__ out) {
  const int b = blockIdx.x;
  __shared__ float p1[3][64];
  __shared__ float p2[3][128];
  const int tid = threadIdx.x;  // 128 threads
  for (int i = tid; i < 192; i += 128) p1[i / 64][i % 64] = pc1buf[b * 192 + i];
  for (int i = tid; i < 384; i += 128) p2[i / 128][i % 128] = pc2xyz[b * 384 + i];
  __syncthreads();
  // pc_low: out[b][pt][c] = p1[c][pt]
  for (int i = tid; i < 192; i += 128) {
    int pt = i / 3, c = i % 3;
    out[b * 192 + i] = p1[c][pt];
  }
  // stage 1: knn(pc1,1) -> exp1 -> pc_middle
  if (tid < 64) {
    const int i = tid;
    float xs0 = p1[0][i], xs1 = p1[1][i], xs2 = p1[2][i];
    float xxi = xs0 * xs0 + xs1 * xs1 + xs2 * xs2;
    float bestv = -INFINITY;
    int besti = 0;
    for (int m = 0; m < 64; m++) {
      float q0 = p1[0][m], q1 = p1[1][m], q2 = p1[2][m];
      float dot = xs0 * q0 + xs1 * q1 + xs2 * q2;
      float inner = -2.0f * dot;
      float pd = -xxi - inner - (q0 * q0 + q1 * q1 + q2 * q2);
      if (pd > bestv) { bestv = pd; besti = m; }
    }
#pragma unroll
    for (int c = 0; c < 3; c++) {
      float ctr = p1[c][i];
      float nb = p1[c][besti];
      float e0 = 2.0f * ctr - nb;
      float e1 = ctr;
      out[768 + b * 384 + (2 * i) * 3 + c] = e0 + p2[c][2 * i];
      out[768 + b * 384 + (2 * i + 1) * 3 + c] = e1 + p2[c][2 * i + 1];
    }
  }
  // stage 2: knn(pc2,3) -> exp2 -> pc_high
  {
    const int j = tid;  // 128 threads
    float xs0 = p2[0][j], xs1 = p2[1][j], xs2 = p2[2][j];
    float xxj = xs0 * xs0 + xs1 * xs1 + xs2 * xs2;
    float bv0 = -INFINITY, bv1 = -INFINITY, bv2 = -INFINITY;
    int bi0 = 0, bi1 = 0, bi2 = 0;
    for (int m = 0; m < 128; m++) {
      float q0 = p2[0][m], q1 = p2[1][m], q2 = p2[2][m];
      float dot = xs0 * q0 + xs1 * q1 + xs2 * q2;
      float inner = -2.0f * dot;
      float pd = -xxj - inner - (q0 * q0 + q1 * q1 + q2 * q2);
      if (pd > bv2) {
        bv2 = pd; bi2 = m;
        if (bv2 > bv1) { float t = bv2; bv2 = bv1; bv1 = t; int ti = bi2; bi2 = bi1; bi1 = ti; }
        if (bv1 > bv0) { float t = bv1; bv1 = bv0; bv0 = t; int ti = bi1; bi1 = bi0; bi0 = ti; }
      }
    }
#pragma unroll
    for (int c = 0; c < 3; c++) {
      float ctr = p2[c][j];
      float e0 = 2.0f * ctr - p2[c][bi0];
      float e1 = 2.0f * ctr - p2[c][bi1];
      float e2 = 2.0f * ctr - p2[c][bi2];
      float e3 = ctr;
      const float* p3 = &pc3xyz[b * 1536 + c * 512];
      out[2304 + b * 1536 + (4 * j + 0) * 3 + c] = e0 + p3[4 * j + 0];
      out[2304 + b * 1536 + (4 * j + 1) * 3 + c] = e1 + p3[4 * j + 1];
      out[2304 + b * 1536 + (4 * j + 2) * 3 + c] = e2 + p3[4 * j + 2];
      out[2304 + b * 1536 + (4 * j + 3) * 3 + c] = e3 + p3[4 * j + 3];
    }
  }
}

extern "C" void kernel_launch(void* const* d_in, const int* in_sizes, int n_in,
                              void* d_out, int out_size, void* d_ws, size_t ws_size,
                              hipStream_t stream) {
  (void)in_sizes; (void)n_in; (void)out_size; (void)ws_size;
  const float* x          = (const float*)d_in[0];
  const float* conv1_w    = (const float*)d_in[1];
  const float* conv2_w    = (const float*)d_in[2];
  const float* conv2_1_w  = (const float*)d_in[3];
  const float* conv3_w    = (const float*)d_in[4];
  const float* conv3_1_w  = (const float*)d_in[5];
  const float* conv4_w    = (const float*)d_in[6];
  const float* conv5_w    = (const float*)d_in[7];
  const float* linear1_w  = (const float*)d_in[8];
  const float* fc1_w      = (const float*)d_in[9];
  const float* fc1_b      = (const float*)d_in[10];
  const float* fc2_w      = (const float*)d_in[11];
  const float* fc2_b      = (const float*)d_in[12];
  const float* fc3_w      = (const float*)d_in[13];
  const float* fc3_b      = (const float*)d_in[14];
  const float* fc1_1_w    = (const float*)d_in[15];
  const float* fc1_1_b    = (const float*)d_in[16];
  const float* fc2_1_w    = (const float*)d_in[17];
  const float* fc2_1_b    = (const float*)d_in[18];
  const float* fc3_1_w    = (const float*)d_in[19];
  const float* fc3_1_b    = (const float*)d_in[20];
  const float* g_conv1_1_w = (const float*)d_in[21];
  const float* g_conv1_1_b = (const float*)d_in[22];
  const float* g_conv1_2_w = (const float*)d_in[23];
  const float* g_conv1_2_b = (const float*)d_in[24];
  const float* g_conv2_1_w = (const float*)d_in[25];
  const float* g_conv2_1_b = (const float*)d_in[26];

  char* ws = (char*)d_ws;
  size_t off = 0;
  auto alloc = [&](size_t bytes) -> void* {
    off = (off + 511) & ~((size_t)511);
    void* p = ws + off;
    off += bytes;
    return p;
  };

  int*    idx0   = (int*)alloc((size_t)RTOT * 16 * 4);
  u64*    pkeys  = (u64*)alloc((size_t)RTOT * 128 * 8);
  float*  ws1    = (float*)alloc((size_t)2 * 64 * 3 * 4);
  float*  ws2    = (float*)alloc((size_t)2 * 64 * 64 * 4);
  float*  ws3    = (float*)alloc((size_t)2 * 128 * 128 * 4);
  float*  ws4    = (float*)alloc((size_t)2 * 512 * 256 * 4);
  float*  ydyc   = (float*)alloc((size_t)RTOT * 1024 * 4);
  float*  xcat   = (float*)alloc((size_t)RTOT * 768 * 4);
  float*  h1     = (float*)alloc((size_t)RTOT * 128 * 4);
  float*  h2     = (float*)alloc((size_t)RTOT * 256 * 4);
  float*  h5     = (float*)alloc((size_t)RTOT * 1024 * 4);
  double* parts  = (double*)alloc((size_t)64 * 1024 * 5 * 8);
  float*  meanb  = (float*)alloc(1024 * 4);
  float*  invb   = (float*)alloc(1024 * 4);
  float*  gpart  = (float*)alloc((size_t)128 * 2048 * 4);
  float*  gvec   = (float*)alloc((size_t)4 * 2048 * 4);
  float*  latent = (float*)alloc((size_t)4 * 2048 * 4);
  float*  x1v    = (float*)alloc((size_t)4 * 1024 * 4);
  float*  x2v    = (float*)alloc((size_t)4 * 512 * 4);
  float*  x3v    = (float*)alloc((size_t)4 * 256 * 4);
  float*  pc1    = (float*)alloc((size_t)4 * 192 * 4);
  float*  pc2f   = (float*)alloc((size_t)4 * 8192 * 4);
  float*  pc2xyz = (float*)alloc((size_t)4 * 384 * 4);
  float*  pc3f   = (float*)alloc((size_t)4 * 65536 * 4);
  float*  pc3f2  = (float*)alloc((size_t)4 * 64 * 512 * 4);
  float*  pc3xyz = (float*)alloc((size_t)4 * 1536 * 4);

  // ---- KNN graph (shared by all edge layers): two-pass register selection
  knn16_part<<<dim3(8, 8, 4), 256, 0, stream>>>(x, pkeys);
  knn16_merge<<<RTOT / 256, 256, 0, stream>>>(pkeys, idx0);

  // ---- conv1 (edge, C=3, O=64) -> xcat cols [0,64)
  prep_edge_w<<<(2 * 64 * 3 + 255) / 256, 256, 0, stream>>>(conv1_w, ws1, 64, 3);
  gemm_f32<<<dim3(2, RTOT / 64), 256, 0, stream>>>(x, 3, ws1, ydyc, 128, 0, 3, 128);
  edge_gather<<<dim3(64, 1), 256, 0, stream>>>(ydyc, idx0, xcat, 768, 0, parts, 64);
  finalize_edge<<<1, 256, 0, stream>>>(parts, meanb, invb, 64, 64);
  bn_apply<<<(RTOT * 64) / 256, 256, 0, stream>>>(xcat, meanb, invb, 64, 768, 0);

  // ---- conv2 (edge, C=64, O=64) -> xcat cols [64,128)
  prep_edge_w<<<(2 * 64 * 64 + 255) / 256, 256, 0, stream>>>(conv2_w, ws2, 64, 64);
  gemm_f32<<<dim3(2, RTOT / 64), 256, 0, stream>>>(xcat, 768, ws2, ydyc, 128, 0, 64, 128);
  edge_gather<<<dim3(64, 1), 256, 0, stream>>>(ydyc, idx0, xcat, 768, 64, parts, 64);
  finalize_edge<<<1, 256, 0, stream>>>(parts, meanb, invb, 64, 64);
  bn_apply<<<(RTOT * 64) / 256, 256, 0, stream>>>(xcat, meanb, invb, 64, 768, 64);

  // ---- conv2_1 (plain, K=128, O=128) -> h1
  gemm_f32<<<dim3(2, RTOT / 64), 256, 0, stream>>>(xcat, 768, conv2_1_w, h1, 128, 0, 128, 128);
  col_stats<<<dim3(64, 1), 256, 0, stream>>>(h1, parts, 128);
  finalize_plain<<<1, 256, 0, stream>>>(parts, meanb, invb, 128, 64);
  bn_apply<<<(RTOT * 128) / 256, 256, 0, stream>>>(h1, meanb, invb, 128, 128, 0);

  // ---- conv3 (edge, C=128, O=128) -> xcat cols [128,256)
  prep_edge_w<<<(2 * 128 * 128 + 255) / 256, 256, 0, stream>>>(conv3_w, ws3, 128, 128);
  gemm_f32<<<dim3(4, RTOT / 64), 256, 0, stream>>>(h1, 128, ws3, ydyc, 256, 0, 128, 256);
  edge_gather<<<dim3(64, 1), 256, 0, stream>>>(ydyc, idx0, xcat, 768, 128, parts, 128);
  finalize_edge<<<1, 256, 0, stream>>>(parts, meanb, invb, 128, 64);
  bn_apply<<<(RTOT * 128) / 256, 256, 0, stream>>>(xcat, meanb, invb, 128, 768, 128);

  // ---- conv3_1 (plain, K=256, O=256) -> h2
  gemm_f32<<<dim3(4, RTOT / 64), 256, 0, stream>>>(xcat, 768, conv3_1_w, h2, 256, 0, 256, 256);
  col_stats<<<dim3(64, 1), 256, 0, stream>>>(h2, parts, 256);
  finalize_plain<<<1, 256, 0, stream>>>(parts, meanb, invb, 256, 64);
  bn_apply<<<(RTOT * 256) / 256, 256, 0, stream>>>(h2, meanb, invb, 256, 256, 0);

  // ---- conv4 (edge, C=256, O=512) -> xcat cols [256,768)
  prep_edge_w<<<(2 * 512 * 256 + 255) / 256, 256, 0, stream>>>(conv4_w, ws4, 512, 256);
  gemm_f32<<<dim3(16, RTOT / 64), 256, 0, stream>>>(h2, 256, ws4, ydyc, 1024, 0, 256, 1024);
  edge_gather<<<dim3(64, 4), 256, 0, stream>>>(ydyc, idx0, xcat, 768, 256, parts, 512);
  finalize_edge<<<2, 256, 0, stream>>>(parts, meanb, invb, 512, 64);
  bn_apply<<<(RTOT * 512) / 256, 256, 0, stream>>>(xcat, meanb, invb, 512, 768, 256);

  // ---- conv5 (plain, K=768, O=1024) -> h5
  gemm_f32<<<dim3(16, RTOT / 64), 256, 0, stream>>>(xcat, 768, conv5_w, h5, 1024, 0, 768, 1024);
  col_stats<<<dim3(64, 4), 256, 0, stream>>>(h5, parts, 1024);
  finalize_plain<<<4, 256, 0, stream>>>(parts, meanb, invb, 1024, 64);
  bn_apply<<<(RTOT * 1024) / 256, 256, 0, stream>>>(h5, meanb, invb, 1024, 1024, 0);

  // ---- g = concat(max, mean)
  reduce_part<<<128, 256, 0, stream>>>(h5, gpart);
  reduce_final<<<16, 256, 0, stream>>>(gpart, gvec);

  // ---- latent
  linear1_bn<<<512, 256, 0, stream>>>(gvec, linear1_w, latent);

  // ---- fc chain
  fc_wave<<<1024 / 16, 256, 4 * 2048 * 4, stream>>>(latent, fc1_w, fc1_b, x1v, 2048, 1024, 1);
  fc_wave<<<512 / 16, 256, 4 * 1024 * 4, stream>>>(x1v, fc2_w, fc2_b, x2v, 1024, 512, 1);
  fc_wave<<<256 / 16, 256, 4 * 512 * 4, stream>>>(x2v, fc3_w, fc3_b, x3v, 512, 256, 1);
  fc_wave<<<192 / 16, 256, 4 * 256 * 4, stream>>>(x3v, fc3_1_w, fc3_1_b, pc1, 256, 192, 0);
  fc_wave<<<8192 / 16, 256, 4 * 512 * 4, stream>>>(x2v, fc2_1_w, fc2_1_b, pc2f, 512, 8192, 1);
  fc_wave<<<65536 / 16, 256, 4 * 1024 * 4, stream>>>(x1v, fc1_1_w, fc1_1_b, pc3f, 1024, 65536, 1);

  // ---- decoder convs
  conv1d_small<<<(4 * 3 * 128 + 255) / 256, 256, 0, stream>>>(pc2f, g_conv2_1_w, g_conv2_1_b,
                                                              pc2xyz, 64, 128, 3, 0);
  conv1d_small<<<(4 * 64 * 512 + 255) / 256, 256, 0, stream>>>(pc3f, g_conv1_1_w, g_conv1_1_b,
                                                               pc3f2, 128, 512, 64, 1);
  conv1d_small<<<(4 * 3 * 512 + 255) / 256, 256, 0, stream>>>(pc3f2, g_conv1_2_w, g_conv1_2_b,
                                                              pc3xyz, 64, 512, 3, 0);

  // ---- mirror expansions + outputs
  finals_kernel<<<4, 128, 0, stream>>>(pc1, pc2xyz, pc3xyz, (float*)d_out);
}

// Round 3
// 1259.410 us; speedup vs baseline: 2.0294x; 1.3568x over previous
//
#include <hip/hip_runtime.h>
#include <math.h>

#define NPTS 2048
#define BATCH 4
#define RTOT 8192   // BATCH*NPTS
#define KNN16 16

typedef unsigned long long u64;
typedef unsigned int u32;
typedef unsigned short ushort16;

using short8  = __attribute__((ext_vector_type(8))) short;
using float4v = __attribute__((ext_vector_type(4))) float;

static __device__ __forceinline__ float lrelu_f(float v) {
  return v >= 0.f ? v : 0.2f * v;
}

// round-to-nearest-even fp32 -> bf16, also return remainder
static __device__ __forceinline__ unsigned short bf16_rne(float f, float* rem) {
  u32 u = __float_as_uint(f);
  u32 r = u + 0x7FFFu + ((u >> 16) & 1u);
  unsigned short h = (unsigned short)(r >> 16);
  *rem = f - __uint_as_float((u32)h << 16);
  return h;
}

// ====================== KNN top-16, two-pass, register CE chain =============
#define REP16(X) X(0) X(1) X(2) X(3) X(4) X(5) X(6) X(7) X(8) X(9) X(10) X(11) X(12) X(13) X(14) X(15)

__global__ __launch_bounds__(256) void knn16_part(const float* __restrict__ x,
                                                  u64* __restrict__ pkeys) {
  __shared__ float4 cand[256];
  const int tid = threadIdx.x;
  const int qchunk = blockIdx.x, slice = blockIdx.y, b = blockIdx.z;
  const float* xb = x + (size_t)b * NPTS * 3;
  {
    const int c = slice * 256 + tid;
    float a0 = xb[c * 3 + 0], a1 = xb[c * 3 + 1], a2 = xb[c * 3 + 2];
    cand[tid] = make_float4(a0, a1, a2, a0 * a0 + a1 * a1 + a2 * a2);
  }
  const int n = qchunk * 256 + tid;
  const float p0 = xb[n * 3 + 0], p1 = xb[n * 3 + 1], p2 = xb[n * 3 + 2];
  const float pw = p0 * p0 + p1 * p1 + p2 * p2;
  __syncthreads();

#define DECLK(k) u64 key##k = 0ull;
  REP16(DECLK)
#undef DECLK
  const int mbase = slice * 256;
  for (int m2 = 0; m2 < 256; m2++) {
    const float4 qd = cand[m2];
    const float dot = p0 * qd.x + p1 * qd.y + p2 * qd.z;
    const float inner = -2.0f * dot;
    const float pd = -pw - inner - qd.w;  // matches reference formula
    u32 s = __float_as_uint(pd);
    s = (s & 0x80000000u) ? ~s : (s | 0x80000000u);
    u64 ck = ((u64)s << 32) | (u32)(2047 - (mbase + m2));
#define CE(k) { const bool sw = ck > key##k; const u64 mx = sw ? ck : key##k; \
                const u64 mn = sw ? key##k : ck; key##k = mx; ck = mn; }
    REP16(CE)
#undef CE
  }
  const size_t q = (size_t)b * NPTS + n;
#define STOREK(k) pkeys[(size_t)(slice * 16 + k) * RTOT + q] = key##k;
  REP16(STOREK)
#undef STOREK
}

__global__ __launch_bounds__(256) void knn16_merge(const u64* __restrict__ pkeys,
                                                   int* __restrict__ idxout) {
  const int q = blockIdx.x * 256 + threadIdx.x;
#define DECLK(k) u64 key##k = 0ull;
  REP16(DECLK)
#undef DECLK
  for (int j = 0; j < 128; j++) {
    u64 ck = pkeys[(size_t)j * RTOT + q];
#define CE(k) { const bool sw = ck > key##k; const u64 mx = sw ? ck : key##k; \
                const u64 mn = sw ? key##k : ck; key##k = mx; ck = mn; }
    REP16(CE)
#undef CE
  }
  int* op = idxout + (size_t)q * KNN16;
#define STOREI(k) op[k] = 2047 - (int)(key##k & 0xFFFFFFFFu);
  REP16(STOREI)
#undef STOREI
}

// -------- stack [W_d ; W_c - W_d] fp32 (conv1 only) -------------------------
__global__ void prep_edge_w(const float* __restrict__ W, float* __restrict__ Wout,
                            int O, int C) {
  int i = blockIdx.x * 256 + threadIdx.x;
  if (i >= 2 * O * C) return;
  int o = i / C, c = i % C;
  Wout[i] = (o < O) ? W[(size_t)o * 2 * C + c]
                    : (W[(size_t)(o - O) * 2 * C + C + c] - W[(size_t)(o - O) * 2 * C + c]);
}

// -------- stack [W_d ; W_c - W_d] and split to bf16 hi/lo -------------------
__global__ void prep_edge_w_split(const float* __restrict__ W,
                                  unsigned short* __restrict__ hi,
                                  unsigned short* __restrict__ lo, int O, int C) {
  int i = blockIdx.x * 256 + threadIdx.x;
  if (i >= 2 * O * C) return;
  int o = i / C, c = i % C;
  float v = (o < O) ? W[(size_t)o * 2 * C + c]
                    : (W[(size_t)(o - O) * 2 * C + C + c] - W[(size_t)(o - O) * 2 * C + c]);
  float rem, rem2;
  hi[i] = bf16_rne(v, &rem);
  lo[i] = bf16_rne(rem, &rem2);
}

// -------- split plain fp32 weight to bf16 hi/lo -----------------------------
__global__ void split_w(const float* __restrict__ W, unsigned short* __restrict__ hi,
                        unsigned short* __restrict__ lo, int n) {
  int i = blockIdx.x * 256 + threadIdx.x;
  if (i >= n) return;
  float rem, rem2;
  hi[i] = bf16_rne(W[i], &rem);
  lo[i] = bf16_rne(rem, &rem2);
}

// -------- fp32 GEMM (conv1 only, K=3) ---------------------------------------
__global__ __launch_bounds__(256) void gemm_f32(
    const float* __restrict__ F, int ldF,
    const float* __restrict__ W,
    float* __restrict__ Out, int ldOut, int outOff,
    int K, int O) {
  __shared__ __align__(16) float Fs[16][68];
  __shared__ __align__(16) float Ws[16][68];
  const int tid = threadIdx.x;
  const int tx = tid & 15;
  const int ty = tid >> 4;
  const int obase = blockIdx.x * 64;
  const int rbase = blockIdx.y * 64;
  float acc[4][4] = {{0.f}};
  for (int k0 = 0; k0 < K; k0 += 16) {
#pragma unroll
    for (int e = 0; e < 4; e++) {
      int ei = tid * 4 + e;
      int rr = ei >> 4;
      int kk = ei & 15;
      int kg = k0 + kk;
      float fv = 0.f, wv = 0.f;
      if (kg < K) {
        fv = F[(size_t)(rbase + rr) * ldF + kg];
        wv = W[(size_t)(obase + rr) * K + kg];
      }
      Fs[kk][rr] = fv;
      Ws[kk][rr] = wv;
    }
    __syncthreads();
#pragma unroll
    for (int kk = 0; kk < 16; kk++) {
      const float4 a = *(const float4*)&Fs[kk][ty * 4];
      const float4 bb = *(const float4*)&Ws[kk][tx * 4];
      float av[4] = {a.x, a.y, a.z, a.w};
      float bvv[4] = {bb.x, bb.y, bb.z, bb.w};
#pragma unroll
      for (int i = 0; i < 4; i++)
#pragma unroll
        for (int j = 0; j < 4; j++) acc[i][j] = fmaf(av[i], bvv[j], acc[i][j]);
    }
    __syncthreads();
  }
#pragma unroll
  for (int i = 0; i < 4; i++) {
    size_t rowp = (size_t)(rbase + ty * 4 + i) * ldOut + outOff + obase + tx * 4;
    float4 v = make_float4(acc[i][0], acc[i][1], acc[i][2], acc[i][3]);
    *(float4*)&Out[rowp] = v;
  }
}

// ============ bf16x3-split MFMA GEMM: Out(r,o) += F[r,:] . W[o,:] ===========
// F given as hi/lo bf16 (row stride ldF), W as hi/lo bf16 (row stride K).
// Block tile 128x128, BK=32, 4 waves in 2x2 of 64x64; per wave 4x4 MFMA tiles.
#define LDSP 40  // padded LDS k-stride (bank-conflict-free)

__global__ __launch_bounds__(256, 2) void gemm_mfma3(
    const unsigned short* __restrict__ Fhi, const unsigned short* __restrict__ Flo, int ldF,
    const unsigned short* __restrict__ Whi, const unsigned short* __restrict__ Wlo,
    float* __restrict__ Out, int ldOut, int outOff, int K) {
  __shared__ __align__(16) unsigned short sF[2][128 * LDSP];
  __shared__ __align__(16) unsigned short sW[2][128 * LDSP];
  const int tid = threadIdx.x;
  const int obase = blockIdx.x * 128;
  const int rbase = blockIdx.y * 128;
  const int wave = tid >> 6, lane = tid & 63;
  const int wrow = (wave >> 1) * 64, wcol = (wave & 1) * 64;
  const int l15 = lane & 15, quad = lane >> 4;

  float4v acc[4][4];
#pragma unroll
  for (int i = 0; i < 4; i++)
#pragma unroll
    for (int j = 0; j < 4; j++) acc[i][j] = (float4v){0.f, 0.f, 0.f, 0.f};

  const int srow = tid >> 1;        // 0..127
  const int skk = (tid & 1) * 16;   // 0 or 16

  for (int k0 = 0; k0 < K; k0 += 32) {
    // ---- stage 128x32 of F(hi,lo) and W(hi,lo) into LDS
    const size_t fbase = (size_t)(rbase + srow) * ldF + k0 + skk;
    const size_t wbase = (size_t)(obase + srow) * K + k0 + skk;
    uint4 fh0 = *(const uint4*)&Fhi[fbase];
    uint4 fh1 = *(const uint4*)&Fhi[fbase + 8];
    uint4 fl0 = *(const uint4*)&Flo[fbase];
    uint4 fl1 = *(const uint4*)&Flo[fbase + 8];
    uint4 wh0 = *(const uint4*)&Whi[wbase];
    uint4 wh1 = *(const uint4*)&Whi[wbase + 8];
    uint4 wl0 = *(const uint4*)&Wlo[wbase];
    uint4 wl1 = *(const uint4*)&Wlo[wbase + 8];
    const int sdst = srow * LDSP + skk;
    *(uint4*)&sF[0][sdst] = fh0;
    *(uint4*)&sF[0][sdst + 8] = fh1;
    *(uint4*)&sF[1][sdst] = fl0;
    *(uint4*)&sF[1][sdst + 8] = fl1;
    *(uint4*)&sW[0][sdst] = wh0;
    *(uint4*)&sW[0][sdst + 8] = wh1;
    *(uint4*)&sW[1][sdst] = wl0;
    *(uint4*)&sW[1][sdst + 8] = wl1;
    __syncthreads();

    // ---- fragment loads (A: rows, B: cols; k = quad*8..+7)
    short8 af[2][4], bf[2][4];
#pragma unroll
    for (int i = 0; i < 4; i++) {
      const int ar = (wrow + i * 16 + l15) * LDSP + quad * 8;
      const int br = (wcol + i * 16 + l15) * LDSP + quad * 8;
      af[0][i] = *(const short8*)&sF[0][ar];
      af[1][i] = *(const short8*)&sF[1][ar];
      bf[0][i] = *(const short8*)&sW[0][br];
      bf[1][i] = *(const short8*)&sW[1][br];
    }
#pragma unroll
    for (int i = 0; i < 4; i++)
#pragma unroll
      for (int j = 0; j < 4; j++) {
        acc[i][j] = __builtin_amdgcn_mfma_f32_16x16x32_bf16(af[0][i], bf[0][j], acc[i][j], 0, 0, 0);
        acc[i][j] = __builtin_amdgcn_mfma_f32_16x16x32_bf16(af[0][i], bf[1][j], acc[i][j], 0, 0, 0);
        acc[i][j] = __builtin_amdgcn_mfma_f32_16x16x32_bf16(af[1][i], bf[0][j], acc[i][j], 0, 0, 0);
      }
    __syncthreads();
  }

  // ---- epilogue: D[row=quad*4+r][col=l15] per 16x16 tile
#pragma unroll
  for (int i = 0; i < 4; i++)
#pragma unroll
    for (int j = 0; j < 4; j++) {
#pragma unroll
      for (int r = 0; r < 4; r++) {
        const int gr = rbase + wrow + i * 16 + quad * 4 + r;
        const int gc = outOff + obase + wcol + j * 16 + l15;
        Out[(size_t)gr * ldOut + gc] = acc[i][j][r];
      }
    }
}

// -------- edge gather: V = Yc + max_k Yd[nbr]; fp64 BN partial stats --------
__global__ __launch_bounds__(256) void edge_gather(
    const float* __restrict__ Y,       // (RTOT, 2O)
    const int* __restrict__ idx,       // (RTOT, 16)
    float* __restrict__ dst, int dstS, int dstOff,
    double* __restrict__ parts,        // [gridDim.x][O][5]
    int O) {
  const int NCH = 128;
  __shared__ int sidx[NCH * KNN16];       // 8KB
  __shared__ double sred[256 * 5];        // 10KB
  const int tid = threadIdx.x;
  const int row0 = blockIdx.x * NCH;
  const int OC = (O < 128) ? O : 128;
  const int subcnt = 256 / OC;
  const int olane = tid % OC;
  const int sub = tid / OC;
  const int o = blockIdx.y * 128 + olane;
  for (int i = tid; i < NCH * KNN16; i += 256) sidx[i] = idx[(size_t)row0 * KNN16 + i];
  __syncthreads();
  const int twoO = 2 * O;
  double s1 = 0, s2 = 0, scr = 0, sc = 0, sc2 = 0;
  for (int nl = sub; nl < NCH; nl += subcnt) {
    const int r = row0 + nl;
    const int bbase = (r >> 11) << 11;  // batch*2048
    const int* ip = &sidx[nl * KNN16];
    float m = -INFINITY, a1 = 0.f, a2 = 0.f;
#pragma unroll
    for (int k = 0; k < KNN16; k++) {
      const int nb = ip[k];
      const float v = Y[(size_t)(bbase + nb) * twoO + o];
      m = fmaxf(m, v);
      a1 += v;
      a2 = fmaf(v, v, a2);
    }
    const float yc = Y[(size_t)r * twoO + O + o];
    dst[(size_t)r * dstS + dstOff + o] = yc + m;
    s1 += a1; s2 += a2; scr += (double)yc * (double)a1;
    sc += yc; sc2 += (double)yc * (double)yc;
  }
  sred[tid * 5 + 0] = s1; sred[tid * 5 + 1] = s2; sred[tid * 5 + 2] = scr;
  sred[tid * 5 + 3] = sc; sred[tid * 5 + 4] = sc2;
  __syncthreads();
  if (sub == 0) {
    for (int j = 1; j < subcnt; j++) {
      const int t2 = tid + j * OC;
      s1 += sred[t2 * 5 + 0]; s2 += sred[t2 * 5 + 1]; scr += sred[t2 * 5 + 2];
      sc += sred[t2 * 5 + 3]; sc2 += sred[t2 * 5 + 4];
    }
    double* pp = &parts[((size_t)blockIdx.x * O + o) * 5];
    pp[0] = s1; pp[1] = s2; pp[2] = scr; pp[3] = sc; pp[4] = sc2;
  }
}

__global__ void finalize_edge(const double* __restrict__ parts, float* __restrict__ mean,
                              float* __restrict__ invs, int O, int nblk) {
  int o = blockIdx.x * 256 + threadIdx.x;
  if (o >= O) return;
  double s1 = 0, s2 = 0, cr = 0, c = 0, c2 = 0;
  for (int k = 0; k < nblk; k++) {
    const double* p = &parts[((size_t)k * O + o) * 5];
    s1 += p[0]; s2 += p[1]; cr += p[2]; c += p[3]; c2 += p[4];
  }
  const double cnt = (double)RTOT * KNN16;
  double m = (s1 + (double)KNN16 * c) / cnt;
  double ev2 = (s2 + 2.0 * cr + (double)KNN16 * c2) / cnt;
  double var = ev2 - m * m;
  mean[o] = (float)m;
  invs[o] = (float)(1.0 / sqrt(var + 1e-5));
}

// -------- plain per-channel stats over (RTOT, O) ----------------------------
__global__ __launch_bounds__(256) void col_stats(const float* __restrict__ X,
                                                 double* __restrict__ parts, int O) {
  const int NCH = 128;
  __shared__ double sred[256 * 2];
  const int tid = threadIdx.x;
  const int row0 = blockIdx.x * NCH;
  const int OC = (O < 256) ? O : 256;
  const int subcnt = 256 / OC;
  const int olane = tid % OC;
  const int sub = tid / OC;
  const int o = blockIdx.y * 256 + olane;
  double s1 = 0, s2 = 0;
  for (int nl = sub; nl < NCH; nl += subcnt) {
    const float v = X[(size_t)(row0 + nl) * O + o];
    s1 += v; s2 += (double)v * (double)v;
  }
  sred[tid * 2 + 0] = s1; sred[tid * 2 + 1] = s2;
  __syncthreads();
  if (sub == 0) {
    for (int j = 1; j < subcnt; j++) {
      s1 += sred[(tid + j * OC) * 2 + 0];
      s2 += sred[(tid + j * OC) * 2 + 1];
    }
    parts[((size_t)blockIdx.x * O + o) * 2 + 0] = s1;
    parts[((size_t)blockIdx.x * O + o) * 2 + 1] = s2;
  }
}

__global__ void finalize_plain(const double* __restrict__ parts, float* __restrict__ mean,
                               float* __restrict__ invs, int O, int nblk) {
  int o = blockIdx.x * 256 + threadIdx.x;
  if (o >= O) return;
  double s1 = 0, s2 = 0;
  for (int k = 0; k < nblk; k++) {
    s1 += parts[((size_t)k * O + o) * 2 + 0];
    s2 += parts[((size_t)k * O + o) * 2 + 1];
  }
  double m = s1 / (double)RTOT;
  double var = s2 / (double)RTOT - m * m;
  mean[o] = (float)m;
  invs[o] = (float)(1.0 / sqrt(var + 1e-5));
}

// -------- BN + LeakyReLU in-place; optionally emit bf16 hi/lo split ---------
__global__ void bn_apply(float* __restrict__ X, const float* __restrict__ mean,
                         const float* __restrict__ invs, int O, int stride, int colOff,
                         unsigned short* __restrict__ hi, unsigned short* __restrict__ lo,
                         int hlStride) {
  size_t i = (size_t)blockIdx.x * 256 + threadIdx.x;
  if (i >= (size_t)RTOT * O) return;
  int o = (int)(i % O);
  size_t r = i / O;
  float* p = &X[r * stride + colOff + o];
  float v = lrelu_f((*p - mean[o]) * invs[o]);
  *p = v;
  if (hi) {
    float rem, rem2;
    size_t hp = r * hlStride + colOff + o;
    hi[hp] = bf16_rne(v, &rem);
    lo[hp] = bf16_rne(rem, &rem2);
  }
}

// -------- g = concat(max_n, mean_n) of H5 (RTOT,1024) -----------------------
__global__ __launch_bounds__(256) void reduce_part(const float* __restrict__ H,
                                                   float* __restrict__ part) {
  const int chunk = blockIdx.x;  // 128 chunks of 64 rows
  const int row0 = chunk * 64;
  const int tid = threadIdx.x;
  float mx[4] = {-INFINITY, -INFINITY, -INFINITY, -INFINITY};
  float sm[4] = {0.f, 0.f, 0.f, 0.f};
  for (int nl = 0; nl < 64; nl++) {
    const float* row = &H[(size_t)(row0 + nl) * 1024];
#pragma unroll
    for (int oi = 0; oi < 4; oi++) {
      float v = row[tid + oi * 256];
      mx[oi] = fmaxf(mx[oi], v);
      sm[oi] += v;
    }
  }
#pragma unroll
  for (int oi = 0; oi < 4; oi++) {
    part[(size_t)chunk * 2048 + tid + oi * 256] = mx[oi];
    part[(size_t)chunk * 2048 + 1024 + tid + oi * 256] = sm[oi];
  }
}

__global__ void reduce_final(const float* __restrict__ part, float* __restrict__ g) {
  int i = blockIdx.x * 256 + threadIdx.x;
  if (i >= 4096) return;
  int b = i >> 10, o = i & 1023;
  float mx = -INFINITY, sm = 0.f;
  for (int c = 0; c < 32; c++) {
    const float* p = &part[(size_t)(b * 32 + c) * 2048];
    mx = fmaxf(mx, p[o]);
    sm += p[1024 + o];
  }
  g[b * 2048 + o] = mx;
  g[b * 2048 + 1024 + o] = sm * (1.0f / 2048.0f);
}

// -------- latent = lrelu(BN_over_batch(g @ W^T)) ----------------------------
__global__ __launch_bounds__(256) void linear1_bn(const float* __restrict__ g,
                                                  const float* __restrict__ W,
                                                  float* __restrict__ latent) {
  __shared__ __align__(16) float sg[4][2048];  // 32KB
  const int tid = threadIdx.x;
  for (int i = tid; i < 4 * 2048; i += 256) sg[i >> 11][i & 2047] = g[i];
  __syncthreads();
  const int wave = tid >> 6, lane = tid & 63;
  const int o = blockIdx.x * 4 + wave;
  const float* wr = &W[(size_t)o * 2048];
  float a0 = 0.f, a1 = 0.f, a2 = 0.f, a3 = 0.f;
  for (int k = lane * 4; k < 2048; k += 256) {
    float4 w4 = *(const float4*)&wr[k];
    float4 x0 = *(const float4*)&sg[0][k];
    float4 x1 = *(const float4*)&sg[1][k];
    float4 x2 = *(const float4*)&sg[2][k];
    float4 x3 = *(const float4*)&sg[3][k];
    a0 += w4.x * x0.x + w4.y * x0.y + w4.z * x0.z + w4.w * x0.w;
    a1 += w4.x * x1.x + w4.y * x1.y + w4.z * x1.z + w4.w * x1.w;
    a2 += w4.x * x2.x + w4.y * x2.y + w4.z * x2.z + w4.w * x2.w;
    a3 += w4.x * x3.x + w4.y * x3.y + w4.z * x3.z + w4.w * x3.w;
  }
  for (int s = 32; s > 0; s >>= 1) {
    a0 += __shfl_down(a0, s); a1 += __shfl_down(a1, s);
    a2 += __shfl_down(a2, s); a3 += __shfl_down(a3, s);
  }
  if (lane == 0) {
    float m = (a0 + a1 + a2 + a3) * 0.25f;
    float d0 = a0 - m, d1 = a1 - m, d2 = a2 - m, d3 = a3 - m;
    float var = (d0 * d0 + d1 * d1 + d2 * d2 + d3 * d3) * 0.25f;
    float inv = 1.0f / sqrtf(var + 1e-5f);
    latent[0 * 2048 + o] = lrelu_f(d0 * inv);
    latent[1 * 2048 + o] = lrelu_f(d1 * inv);
    latent[2 * 2048 + o] = lrelu_f(d2 * inv);
    latent[3 * 2048 + o] = lrelu_f(d3 * inv);
  }
}

// -------- generic fc: out[b][o] = act(dot(X[b], W[o]) + bias[o]) ------------
__global__ __launch_bounds__(256) void fc_wave(const float* __restrict__ X,  // (4,K)
                                               const float* __restrict__ W,
                                               const float* __restrict__ bias,
                                               float* __restrict__ out,
                                               int K, int O, int relu) {
  extern __shared__ float sx[];  // 4*K
  const int tid = threadIdx.x;
  for (int i = tid; i < 4 * K; i += 256) sx[i] = X[i];
  __syncthreads();
  const int wave = tid >> 6, lane = tid & 63;
#pragma unroll
  for (int oi = 0; oi < 4; oi++) {
    const int o = blockIdx.x * 16 + wave * 4 + oi;
    if (o >= O) continue;
    const float* wr = &W[(size_t)o * K];
    float a0 = 0.f, a1 = 0.f, a2 = 0.f, a3 = 0.f;
    for (int k = lane * 4; k < K; k += 256) {
      float4 w4 = *(const float4*)&wr[k];
      float4 x0 = *(const float4*)&sx[0 * K + k];
      float4 x1 = *(const float4*)&sx[1 * K + k];
      float4 x2 = *(const float4*)&sx[2 * K + k];
      float4 x3 = *(const float4*)&sx[3 * K + k];
      a0 += w4.x * x0.x + w4.y * x0.y + w4.z * x0.z + w4.w * x0.w;
      a1 += w4.x * x1.x + w4.y * x1.y + w4.z * x1.z + w4.w * x1.w;
      a2 += w4.x * x2.x + w4.y * x2.y + w4.z * x2.z + w4.w * x2.w;
      a3 += w4.x * x3.x + w4.y * x3.y + w4.z * x3.z + w4.w * x3.w;
    }
    for (int s = 32; s > 0; s >>= 1) {
      a0 += __shfl_down(a0, s); a1 += __shfl_down(a1, s);
      a2 += __shfl_down(a2, s); a3 += __shfl_down(a3, s);
    }
    if (lane == 0) {
      float bb = bias[o];
      float v0 = a0 + bb, v1 = a1 + bb, v2 = a2 + bb, v3 = a3 + bb;
      if (relu) {
        v0 = fmaxf(v0, 0.f); v1 = fmaxf(v1, 0.f);
        v2 = fmaxf(v2, 0.f); v3 = fmaxf(v3, 0.f);
      }
      out[0 * O + o] = v0; out[1 * O + o] = v1;
      out[2 * O + o] = v2; out[3 * O + o] = v3;
    }
  }
}

// -------- small conv1d: out[b][o][j] = act(sum_c W[o][c] X[b][c][j] + b) ----
__global__ void conv1d_small(const float* __restrict__ X, const float* __restrict__ W,
                             const float* __restrict__ bias, float* __restrict__ out,
                             int C, int J, int O2, int relu) {
  int i = blockIdx.x * 256 + threadIdx.x;
  if (i >= 4 * O2 * J) return;
  int j = i % J;
  int o = (i / J) % O2;
  int b = i / (J * O2);
  const float* xb = &X[(size_t)b * C * J + j];
  const float* wr = &W[(size_t)o * C];
  float a = 0.f;
  for (int c = 0; c < C; c++) a = fmaf(wr[c], xb[(size_t)c * J], a);
  a += bias[o];
  if (relu) a = fmaxf(a, 0.f);
  out[i] = a;
}

// -------- mirror expansions + final outputs ---------------------------------
__global__ void finals_kernel(const float* __restrict__ pc1buf,   // (B,3,64)
                              const float* __restrict__ pc2xyz,   // (B,3,128)
                              const float* __restrict__ pc3xyz,   // (B,3,512)
                              float* __restrict__ out) {
  const int b = blockIdx.x;
  __shared__ float p1[3][64];
  __shared__ float p2[3][128];
  const int tid = threadIdx.x;  // 128 threads
  for (int i = tid; i < 192; i += 128) p1[i / 64][i % 64] = pc1buf[b * 192 + i];
  for (int i = tid; i < 384; i += 128) p2[i / 128][i % 128] = pc2xyz[b * 384 + i];
  __syncthreads();
  for (int i = tid; i < 192; i += 128) {
    int pt = i / 3, c = i % 3;
    out[b * 192 + i] = p1[c][pt];
  }
  if (tid < 64) {
    const int i = tid;
    float xs0 = p1[0][i], xs1 = p1[1][i], xs2 = p1[2][i];
    float xxi = xs0 * xs0 + xs1 * xs1 + xs2 * xs2;
    float bestv = -INFINITY;
    int besti = 0;
    for (int m = 0; m < 64; m++) {
      float q0 = p1[0][m], q1 = p1[1][m], q2 = p1[2][m];
      float dot = xs0 * q0 + xs1 * q1 + xs2 * q2;
      float inner = -2.0f * dot;
      float pd = -xxi - inner - (q0 * q0 + q1 * q1 + q2 * q2);
      if (pd > bestv) { bestv = pd; besti = m; }
    }
#pragma unroll
    for (int c = 0; c < 3; c++) {
      float ctr = p1[c][i];
      float nb = p1[c][besti];
      float e0 = 2.0f * ctr - nb;
      float e1 = ctr;
      out[768 + b * 384 + (2 * i) * 3 + c] = e0 + p2[c][2 * i];
      out[768 + b * 384 + (2 * i + 1) * 3 + c] = e1 + p2[c][2 * i + 1];
    }
  }
  {
    const int j = tid;  // 128 threads
    float xs0 = p2[0][j], xs1 = p2[1][j], xs2 = p2[2][j];
    float xxj = xs0 * xs0 + xs1 * xs1 + xs2 * xs2;
    float bv0 = -INFINITY, bv1 = -INFINITY, bv2 = -INFINITY;
    int bi0 = 0, bi1 = 0, bi2 = 0;
    for (int m = 0; m < 128; m++) {
      float q0 = p2[0][m], q1 = p2[1][m], q2 = p2[2][m];
      float dot = xs0 * q0 + xs1 * q1 + xs2 * q2;
      float inner = -2.0f * dot;
      float pd = -xxj - inner - (q0 * q0 + q1 * q1 + q2 * q2);
      if (pd > bv2) {
        bv2 = pd; bi2 = m;
        if (bv2 > bv1) { float t = bv2; bv2 = bv1; bv1 = t; int ti = bi2; bi2 = bi1; bi1 = ti; }
        if (bv1 > bv0) { float t = bv1; bv1 = bv0; bv0 = t; int ti = bi1; bi1 = bi0; bi0 = ti; }
      }
    }
#pragma unroll
    for (int c = 0; c < 3; c++) {
      float ctr = p2[c][j];
      float e0 = 2.0f * ctr - p2[c][bi0];
      float e1 = 2.0f * ctr - p2[c][bi1];
      float e2 = 2.0f * ctr - p2[c][bi2];
      float e3 = ctr;
      const float* p3 = &pc3xyz[b * 1536 + c * 512];
      out[2304 + b * 1536 + (4 * j + 0) * 3 + c] = e0 + p3[4 * j + 0];
      out[2304 + b * 1536 + (4 * j + 1) * 3 + c] = e1 + p3[4 * j + 1];
      out[2304 + b * 1536 + (4 * j + 2) * 3 + c] = e2 + p3[4 * j + 2];
      out[2304 + b * 1536 + (4 * j + 3) * 3 + c] = e3 + p3[4 * j + 3];
    }
  }
}

extern "C" void kernel_launch(void* const* d_in, const int* in_sizes, int n_in,
                              void* d_out, int out_size, void* d_ws, size_t ws_size,
                              hipStream_t stream) {
  (void)in_sizes; (void)n_in; (void)out_size; (void)ws_size;
  const float* x          = (const float*)d_in[0];
  const float* conv1_w    = (const float*)d_in[1];
  const float* conv2_w    = (const float*)d_in[2];
  const float* conv2_1_w  = (const float*)d_in[3];
  const float* conv3_w    = (const float*)d_in[4];
  const float* conv3_1_w  = (const float*)d_in[5];
  const float* conv4_w    = (const float*)d_in[6];
  const float* conv5_w    = (const float*)d_in[7];
  const float* linear1_w  = (const float*)d_in[8];
  const float* fc1_w      = (const float*)d_in[9];
  const float* fc1_b      = (const float*)d_in[10];
  const float* fc2_w      = (const float*)d_in[11];
  const float* fc2_b      = (const float*)d_in[12];
  const float* fc3_w      = (const float*)d_in[13];
  const float* fc3_b      = (const float*)d_in[14];
  const float* fc1_1_w    = (const float*)d_in[15];
  const float* fc1_1_b    = (const float*)d_in[16];
  const float* fc2_1_w    = (const float*)d_in[17];
  const float* fc2_1_b    = (const float*)d_in[18];
  const float* fc3_1_w    = (const float*)d_in[19];
  const float* fc3_1_b    = (const float*)d_in[20];
  const float* g_conv1_1_w = (const float*)d_in[21];
  const float* g_conv1_1_b = (const float*)d_in[22];
  const float* g_conv1_2_w = (const float*)d_in[23];
  const float* g_conv1_2_b = (const float*)d_in[24];
  const float* g_conv2_1_w = (const float*)d_in[25];
  const float* g_conv2_1_b = (const float*)d_in[26];

  char* ws = (char*)d_ws;
  size_t off = 0;
  auto alloc = [&](size_t bytes) -> void* {
    off = (off + 511) & ~((size_t)511);
    void* p = ws + off;
    off += bytes;
    return p;
  };

  typedef unsigned short ush;
  int*    idx0   = (int*)alloc((size_t)RTOT * 16 * 4);
  u64*    pkeys  = (u64*)alloc((size_t)RTOT * 128 * 8);  // dead after knn; reused for h1 splits
  float*  ws1    = (float*)alloc((size_t)2 * 64 * 3 * 4);
  float*  ydyc   = (float*)alloc((size_t)RTOT * 1024 * 4);
  float*  xcat   = (float*)alloc((size_t)RTOT * 768 * 4);
  float*  h1     = (float*)alloc((size_t)RTOT * 128 * 4);
  float*  h2     = (float*)alloc((size_t)RTOT * 256 * 4);
  float*  h5     = (float*)alloc((size_t)RTOT * 1024 * 4);
  double* parts  = (double*)alloc((size_t)64 * 1024 * 5 * 8);
  float*  meanb  = (float*)alloc(1024 * 4);
  float*  invb   = (float*)alloc(1024 * 4);
  float*  gpart  = (float*)alloc((size_t)128 * 2048 * 4);
  float*  gvec   = (float*)alloc((size_t)4 * 2048 * 4);
  float*  latent = (float*)alloc((size_t)4 * 2048 * 4);
  float*  x1v    = (float*)alloc((size_t)4 * 1024 * 4);
  float*  x2v    = (float*)alloc((size_t)4 * 512 * 4);
  float*  x3v    = (float*)alloc((size_t)4 * 256 * 4);
  float*  pc1    = (float*)alloc((size_t)4 * 192 * 4);
  float*  pc2f   = (float*)alloc((size_t)4 * 8192 * 4);
  float*  pc2xyz = (float*)alloc((size_t)4 * 384 * 4);
  float*  pc3f   = (float*)alloc((size_t)4 * 65536 * 4);
  float*  pc3f2  = (float*)alloc((size_t)4 * 64 * 512 * 4);
  float*  pc3xyz = (float*)alloc((size_t)4 * 1536 * 4);
  // bf16 split activations
  ush* xcat_hi = (ush*)alloc((size_t)RTOT * 768 * 2);
  ush* xcat_lo = (ush*)alloc((size_t)RTOT * 768 * 2);
  ush* h2_hi   = (ush*)alloc((size_t)RTOT * 256 * 2);
  ush* h2_lo   = (ush*)alloc((size_t)RTOT * 256 * 2);
  ush* h1_hi   = (ush*)pkeys;                       // alias (pkeys dead post-knn)
  ush* h1_lo   = (ush*)pkeys + (size_t)RTOT * 128;
  // bf16 split weights
  ush* ws2hi = (ush*)alloc((size_t)128 * 64 * 2);
  ush* ws2lo = (ush*)alloc((size_t)128 * 64 * 2);
  ush* c21hi = (ush*)alloc((size_t)128 * 128 * 2);
  ush* c21lo = (ush*)alloc((size_t)128 * 128 * 2);
  ush* ws3hi = (ush*)alloc((size_t)256 * 128 * 2);
  ush* ws3lo = (ush*)alloc((size_t)256 * 128 * 2);
  ush* c31hi = (ush*)alloc((size_t)256 * 256 * 2);
  ush* c31lo = (ush*)alloc((size_t)256 * 256 * 2);
  ush* ws4hi = (ush*)alloc((size_t)1024 * 256 * 2);
  ush* ws4lo = (ush*)alloc((size_t)1024 * 256 * 2);
  ush* c5hi  = (ush*)alloc((size_t)1024 * 768 * 2);
  ush* c5lo  = (ush*)alloc((size_t)1024 * 768 * 2);

  // ---- weight preps (independent; front-loaded)
  prep_edge_w<<<(2 * 64 * 3 + 255) / 256, 256, 0, stream>>>(conv1_w, ws1, 64, 3);
  prep_edge_w_split<<<(2 * 64 * 64 + 255) / 256, 256, 0, stream>>>(conv2_w, ws2hi, ws2lo, 64, 64);
  split_w<<<(128 * 128 + 255) / 256, 256, 0, stream>>>(conv2_1_w, c21hi, c21lo, 128 * 128);
  prep_edge_w_split<<<(2 * 128 * 128 + 255) / 256, 256, 0, stream>>>(conv3_w, ws3hi, ws3lo, 128, 128);
  split_w<<<(256 * 256 + 255) / 256, 256, 0, stream>>>(conv3_1_w, c31hi, c31lo, 256 * 256);
  prep_edge_w_split<<<(2 * 512 * 256 + 255) / 256, 256, 0, stream>>>(conv4_w, ws4hi, ws4lo, 512, 256);
  split_w<<<(1024 * 768 + 255) / 256, 256, 0, stream>>>(conv5_w, c5hi, c5lo, 1024 * 768);

  // ---- KNN graph
  knn16_part<<<dim3(8, 8, 4), 256, 0, stream>>>(x, pkeys);
  knn16_merge<<<RTOT / 256, 256, 0, stream>>>(pkeys, idx0);

  // ---- conv1 (edge, C=3, O=64, fp32) -> xcat cols [0,64)
  gemm_f32<<<dim3(2, RTOT / 64), 256, 0, stream>>>(x, 3, ws1, ydyc, 128, 0, 3, 128);
  edge_gather<<<dim3(64, 1), 256, 0, stream>>>(ydyc, idx0, xcat, 768, 0, parts, 64);
  finalize_edge<<<1, 256, 0, stream>>>(parts, meanb, invb, 64, 64);
  bn_apply<<<(RTOT * 64) / 256, 256, 0, stream>>>(xcat, meanb, invb, 64, 768, 0,
                                                  xcat_hi, xcat_lo, 768);

  // ---- conv2 (edge, C=64, O=64) -> xcat cols [64,128)
  gemm_mfma3<<<dim3(1, 64), 256, 0, stream>>>(xcat_hi, xcat_lo, 768, ws2hi, ws2lo,
                                              ydyc, 128, 0, 64);
  edge_gather<<<dim3(64, 1), 256, 0, stream>>>(ydyc, idx0, xcat, 768, 64, parts, 64);
  finalize_edge<<<1, 256, 0, stream>>>(parts, meanb, invb, 64, 64);
  bn_apply<<<(RTOT * 64) / 256, 256, 0, stream>>>(xcat, meanb, invb, 64, 768, 64,
                                                  xcat_hi, xcat_lo, 768);

  // ---- conv2_1 (plain, K=128, O=128) -> h1
  gemm_mfma3<<<dim3(1, 64), 256, 0, stream>>>(xcat_hi, xcat_lo, 768, c21hi, c21lo,
                                              h1, 128, 0, 128);
  col_stats<<<dim3(64, 1), 256, 0, stream>>>(h1, parts, 128);
  finalize_plain<<<1, 256, 0, stream>>>(parts, meanb, invb, 128, 64);
  bn_apply<<<(RTOT * 128) / 256, 256, 0, stream>>>(h1, meanb, invb, 128, 128, 0,
                                                   h1_hi, h1_lo, 128);

  // ---- conv3 (edge, C=128, O=128) -> xcat cols [128,256)
  gemm_mfma3<<<dim3(2, 64), 256, 0, stream>>>(h1_hi, h1_lo, 128, ws3hi, ws3lo,
                                              ydyc, 256, 0, 128);
  edge_gather<<<dim3(64, 1), 256, 0, stream>>>(ydyc, idx0, xcat, 768, 128, parts, 128);
  finalize_edge<<<1, 256, 0, stream>>>(parts, meanb, invb, 128, 64);
  bn_apply<<<(RTOT * 128) / 256, 256, 0, stream>>>(xcat, meanb, invb, 128, 768, 128,
                                                   xcat_hi, xcat_lo, 768);

  // ---- conv3_1 (plain, K=256, O=256) -> h2
  gemm_mfma3<<<dim3(2, 64), 256, 0, stream>>>(xcat_hi, xcat_lo, 768, c31hi, c31lo,
                                              h2, 256, 0, 256);
  col_stats<<<dim3(64, 1), 256, 0, stream>>>(h2, parts, 256);
  finalize_plain<<<1, 256, 0, stream>>>(parts, meanb, invb, 256, 64);
  bn_apply<<<(RTOT * 256) / 256, 256, 0, stream>>>(h2, meanb, invb, 256, 256, 0,
                                                   h2_hi, h2_lo, 256);

  // ---- conv4 (edge, C=256, O=512) -> xcat cols [256,768)
  gemm_mfma3<<<dim3(8, 64), 256, 0, stream>>>(h2_hi, h2_lo, 256, ws4hi, ws4lo,
                                              ydyc, 1024, 0, 256);
  edge_gather<<<dim3(64, 4), 256, 0, stream>>>(ydyc, idx0, xcat, 768, 256, parts, 512);
  finalize_edge<<<2, 256, 0, stream>>>(parts, meanb, invb, 512, 64);
  bn_apply<<<(RTOT * 512) / 256, 256, 0, stream>>>(xcat, meanb, invb, 512, 768, 256,
                                                   xcat_hi, xcat_lo, 768);

  // ---- conv5 (plain, K=768, O=1024) -> h5
  gemm_mfma3<<<dim3(8, 64), 256, 0, stream>>>(xcat_hi, xcat_lo, 768, c5hi, c5lo,
                                              h5, 1024, 0, 768);
  col_stats<<<dim3(64, 4), 256, 0, stream>>>(h5, parts, 1024);
  finalize_plain<<<4, 256, 0, stream>>>(parts, meanb, invb, 1024, 64);
  bn_apply<<<(RTOT * 1024) / 256, 256, 0, stream>>>(h5, meanb, invb, 1024, 1024, 0,
                                                    (ush*)nullptr, (ush*)nullptr, 0);

  // ---- g = concat(max, mean)
  reduce_part<<<128, 256, 0, stream>>>(h5, gpart);
  reduce_final<<<16, 256, 0, stream>>>(gpart, gvec);

  // ---- latent
  linear1_bn<<<512, 256, 0, stream>>>(gvec, linear1_w, latent);

  // ---- fc chain
  fc_wave<<<1024 / 16, 256, 4 * 2048 * 4, stream>>>(latent, fc1_w, fc1_b, x1v, 2048, 1024, 1);
  fc_wave<<<512 / 16, 256, 4 * 1024 * 4, stream>>>(x1v, fc2_w, fc2_b, x2v, 1024, 512, 1);
  fc_wave<<<256 / 16, 256, 4 * 512 * 4, stream>>>(x2v, fc3_w, fc3_b, x3v, 512, 256, 1);
  fc_wave<<<192 / 16, 256, 4 * 256 * 4, stream>>>(x3v, fc3_1_w, fc3_1_b, pc1, 256, 192, 0);
  fc_wave<<<8192 / 16, 256, 4 * 512 * 4, stream>>>(x2v, fc2_1_w, fc2_1_b, pc2f, 512, 8192, 1);
  fc_wave<<<65536 / 16, 256, 4 * 1024 * 4, stream>>>(x1v, fc1_1_w, fc1_1_b, pc3f, 1024, 65536, 1);

  // ---- decoder convs
  conv1d_small<<<(4 * 3 * 128 + 255) / 256, 256, 0, stream>>>(pc2f, g_conv2_1_w, g_conv2_1_b,
                                                              pc2xyz, 64, 128, 3, 0);
  conv1d_small<<<(4 * 64 * 512 + 255) / 256, 256, 0, stream>>>(pc3f, g_conv1_1_w, g_conv1_1_b,
                                                               pc3f2, 128, 512, 64, 1);
  conv1d_small<<<(4 * 3 * 512 + 255) / 256, 256, 0, stream>>>(pc3f2, g_conv1_2_w, g_conv1_2_b,
                                                              pc3xyz, 64, 512, 3, 0);

  // ---- mirror expansions + outputs
  finals_kernel<<<4, 128, 0, stream>>>(pc1, pc2xyz, pc3xyz, (float*)d_out);
}